// Round 1
// baseline (558.277 us; speedup 1.0000x reference)
//
#include <hip/hip_runtime.h>
#include <hip/hip_bf16.h>
#include <math.h>

// ---------------------------------------------------------------------------
// GPT2 attention block: out = Attn(h) for B=4, S=2048, H=2048, nh=16, hd=128
// Pipeline (all bf16 MFMA, fp32 accumulate):
//   1) cvt fp32->bf16: h, [Wq;Wk;Wv] (concat), Wo
//   2) gemm_qkv: [8192x2048] @ [6144x2048]^T + bias -> Q,K,V in [bh][S][128]
//   3) attn: causal flash attention per (bh, 128-row Q tile) -> O [B,S,H] bf16
//   4) gemm_out: O @ Wo^T + bo -> fp32 d_out
// ---------------------------------------------------------------------------

using bf16x8 = __attribute__((ext_vector_type(8))) __bf16;
using f32x4  = __attribute__((ext_vector_type(4))) float;
using s16x8  = __attribute__((ext_vector_type(8))) short;

#define MFMA16(a, b, c) __builtin_amdgcn_mfma_f32_16x16x32_bf16((a), (b), (c), 0, 0, 0)

__device__ __forceinline__ unsigned short f2bf(float f) {
  unsigned u = __float_as_uint(f);
  u += 0x7FFFu + ((u >> 16) & 1u);   // round-to-nearest-even (finite inputs only)
  return (unsigned short)(u >> 16);
}

__device__ __forceinline__ void gload16(const void* g, void* l) {
  __builtin_amdgcn_global_load_lds((const __attribute__((address_space(1))) void*)g,
                                   (__attribute__((address_space(3))) void*)l,
                                   16, 0, 0);
}

// ---------------------------------------------------------------------------
// fp32 -> bf16 convert, 4 elems/thread
// ---------------------------------------------------------------------------
__global__ void cvt_kernel(const float* __restrict__ in, unsigned short* __restrict__ out, int n4) {
  int i = blockIdx.x * 256 + threadIdx.x;
  if (i >= n4) return;
  float4 v = ((const float4*)in)[i];
  ushort4 o;
  o.x = f2bf(v.x); o.y = f2bf(v.y); o.z = f2bf(v.z); o.w = f2bf(v.w);
  ((ushort4*)out)[i] = o;
}

// ---------------------------------------------------------------------------
// QKV GEMM: C[m,n] = sum_k A[m,k] * W[n,k] + bias[n], m<8192, n<6144, K=2048
// 128x128 tile, BK=32, 4 waves (2x2), each wave 64x64 (4x4 16x16 frags).
// Output scattered into Q/K/V [b,nh,S,hd] bf16.
// ---------------------------------------------------------------------------
__global__ __launch_bounds__(256, 2)
void gemm_qkv(const unsigned short* __restrict__ A,
              const unsigned short* __restrict__ W,
              const float* __restrict__ bq, const float* __restrict__ bk,
              const float* __restrict__ bv,
              unsigned short* __restrict__ Q, unsigned short* __restrict__ Kq,
              unsigned short* __restrict__ V) {
  __shared__ unsigned short lA[128 * 32];
  __shared__ unsigned short lB[128 * 32];
  const int tid = threadIdx.x;
  const int wave = tid >> 6, lane = tid & 63;
  const int lo = lane & 15, hi = lane >> 4;
  const int bm = blockIdx.x & 63;      // 64 m-blocks
  const int bn = blockIdx.x >> 6;      // 48 n-blocks
  const int m0 = bm * 128, n0 = bn * 128;
  const int wm = (wave >> 1) * 64, wn = (wave & 1) * 64;
  const int r4 = lane >> 2, c4 = lane & 3;     // staging sub-indices
  const int K = 2048;

  f32x4 acc[4][4] = {};

  for (int k0 = 0; k0 < K; k0 += 32) {
    __syncthreads();
#pragma unroll
    for (int j = 0; j < 2; j++) {
      int c = wave * 2 + j;
      const unsigned short* ga = A + (size_t)(m0 + c * 16 + r4) * K + k0 + c4 * 8;
      gload16(ga, &lA[c * 512]);
      const unsigned short* gb = W + (size_t)(n0 + c * 16 + r4) * K + k0 + c4 * 8;
      gload16(gb, &lB[c * 512]);
    }
    __syncthreads();
    bf16x8 af[4], bf_[4];
#pragma unroll
    for (int t = 0; t < 4; t++) {
      af[t]  = *(const bf16x8*)&lA[(wm + t * 16 + lo) * 32 + hi * 8];
      bf_[t] = *(const bf16x8*)&lB[(wn + t * 16 + lo) * 32 + hi * 8];
    }
#pragma unroll
    for (int mi = 0; mi < 4; mi++)
#pragma unroll
      for (int ni = 0; ni < 4; ni++)
        acc[mi][ni] = MFMA16(af[mi], bf_[ni], acc[mi][ni]);
  }

  // epilogue: which of Q/K/V is uniform per block (2048 % 128 == 0)
  const int which = n0 >> 11;
  const float* bias = (which == 0) ? bq : (which == 1) ? bk : bv;
  unsigned short* dst = (which == 0) ? Q : (which == 1) ? Kq : V;
#pragma unroll
  for (int mi = 0; mi < 4; mi++)
#pragma unroll
    for (int ni = 0; ni < 4; ni++) {
      int n_g = n0 + wn + ni * 16 + lo;
      int n2 = n_g & 2047;
      int head = n2 >> 7, d = n2 & 127;
      float bb = bias[n2];
#pragma unroll
      for (int i = 0; i < 4; i++) {
        int m = m0 + wm + mi * 16 + hi * 4 + i;
        int b = m >> 11, s = m & 2047;
        dst[(((size_t)b * 16 + head) * 2048 + s) * 128 + d] = f2bf(acc[mi][ni][i] + bb);
      }
    }
}

// ---------------------------------------------------------------------------
// Output GEMM: out[m,n] = sum_k O[m,k] * Wo[n,k] + bo[n], fp32 out. N=2048.
// ---------------------------------------------------------------------------
__global__ __launch_bounds__(256, 2)
void gemm_out(const unsigned short* __restrict__ A,
              const unsigned short* __restrict__ W,
              const float* __restrict__ bo, float* __restrict__ out) {
  __shared__ unsigned short lA[128 * 32];
  __shared__ unsigned short lB[128 * 32];
  const int tid = threadIdx.x;
  const int wave = tid >> 6, lane = tid & 63;
  const int lo = lane & 15, hi = lane >> 4;
  const int bm = blockIdx.x & 63;      // 64 m-blocks
  const int bn = blockIdx.x >> 6;      // 16 n-blocks
  const int m0 = bm * 128, n0 = bn * 128;
  const int wm = (wave >> 1) * 64, wn = (wave & 1) * 64;
  const int r4 = lane >> 2, c4 = lane & 3;
  const int K = 2048;

  f32x4 acc[4][4] = {};

  for (int k0 = 0; k0 < K; k0 += 32) {
    __syncthreads();
#pragma unroll
    for (int j = 0; j < 2; j++) {
      int c = wave * 2 + j;
      const unsigned short* ga = A + (size_t)(m0 + c * 16 + r4) * K + k0 + c4 * 8;
      gload16(ga, &lA[c * 512]);
      const unsigned short* gb = W + (size_t)(n0 + c * 16 + r4) * K + k0 + c4 * 8;
      gload16(gb, &lB[c * 512]);
    }
    __syncthreads();
    bf16x8 af[4], bf_[4];
#pragma unroll
    for (int t = 0; t < 4; t++) {
      af[t]  = *(const bf16x8*)&lA[(wm + t * 16 + lo) * 32 + hi * 8];
      bf_[t] = *(const bf16x8*)&lB[(wn + t * 16 + lo) * 32 + hi * 8];
    }
#pragma unroll
    for (int mi = 0; mi < 4; mi++)
#pragma unroll
      for (int ni = 0; ni < 4; ni++)
        acc[mi][ni] = MFMA16(af[mi], bf_[ni], acc[mi][ni]);
  }

#pragma unroll
  for (int mi = 0; mi < 4; mi++)
#pragma unroll
    for (int ni = 0; ni < 4; ni++) {
      int n_g = n0 + wn + ni * 16 + lo;
      float bb = bo[n_g];
#pragma unroll
      for (int i = 0; i < 4; i++) {
        int m = m0 + wm + mi * 16 + hi * 4 + i;
        out[(size_t)m * 2048 + n_g] = acc[mi][ni][i] + bb;
      }
    }
}

// ---------------------------------------------------------------------------
// Causal flash attention. Grid: 64 (bh) x 16 (q-tiles of 128). 4 waves/block,
// wave w owns rows q0 = qt*128 + w*32 .. +31 (2 m-frags of 16).
// K-tile (32 keys) staged in LDS with XOR swizzle (byte ^= (row&7)<<4) via
// pre-swizzled global_load_lds source; V staged transposed into padded LDS.
// ---------------------------------------------------------------------------
__global__ __launch_bounds__(256, 2)
void attn_kernel(const unsigned short* __restrict__ Qb,
                 const unsigned short* __restrict__ Kb,
                 const unsigned short* __restrict__ Vb,
                 unsigned short* __restrict__ Ob) {
  __shared__ unsigned short lK[32 * 128];       // swizzled row-major [32][128]
  __shared__ unsigned short lVt[128 * 40];      // V^T [128 d][32 k], pad to 40
  __shared__ unsigned short lP[4][32 * 40];     // per-wave P tile [32 q][32 k], pad 40

  const int tid = threadIdx.x;
  const int wave = tid >> 6, lane = tid & 63;
  const int lo = lane & 15, hi = lane >> 4;
  const int bh = blockIdx.x & 63;
  const int qt = 15 - (blockIdx.x >> 6);        // heavy tiles dispatched first
  const int q0 = qt * 128 + wave * 32;
  const size_t base = (size_t)bh * 2048 * 128;
  const float scale = 0.08838834764831845f;     // 1/sqrt(128)

  // Q fragments in registers: rows q0+mi*16+lo, d = dk*32 + hi*8 ..+7
  bf16x8 aq[2][4];
#pragma unroll
  for (int mi = 0; mi < 2; mi++)
#pragma unroll
    for (int dk = 0; dk < 4; dk++)
      aq[mi][dk] = *(const bf16x8*)&Qb[base + (size_t)(q0 + mi * 16 + lo) * 128 + dk * 32 + hi * 8];

  f32x4 acc[2][8] = {};
  float mrun[2][4], lrun[2][4];
#pragma unroll
  for (int a = 0; a < 2; a++)
#pragma unroll
    for (int b = 0; b < 4; b++) { mrun[a][b] = -INFINITY; lrun[a][b] = 0.0f; }

  const int ktn = qt * 4 + 4;                   // tiles covering k <= q0_block+127
  const int qmax_w = q0 + 31;

  for (int kt = 0; kt < ktn; kt++) {
    __syncthreads();
    // ---- stage K tile (swizzled source -> linear LDS dest) ----
#pragma unroll
    for (int j = 0; j < 2; j++) {
      int c = wave * 2 + j;
      int row = c * 4 + hi;                                  // 0..31
      int srccol = (lo * 16) ^ ((row & 7) << 4);             // byte offset in 256B row
      const unsigned short* g = Kb + base + (size_t)(kt * 32 + row) * 128 + (srccol >> 1);
      gload16(g, &lK[c * 512]);
    }
    // ---- stage V transposed: thread -> rows {2rr,2rr+1}, cols c0..c0+7 ----
    {
      int rr = tid & 15;
      int c0 = (tid >> 4) * 8;
      const unsigned short* vp = Vb + base + (size_t)(kt * 32 + 2 * rr) * 128 + c0;
      s16x8 va = *(const s16x8*)vp;
      s16x8 vb2 = *(const s16x8*)(vp + 128);
#pragma unroll
      for (int j = 0; j < 8; j++)
        *(ushort2*)&lVt[(c0 + j) * 40 + 2 * rr] =
            make_ushort2((unsigned short)va[j], (unsigned short)vb2[j]);
    }
    __syncthreads();

    if (kt * 32 <= qmax_w) {                    // wave-uniform: tile not fully masked
      // ---- scores: S[32q][32k] ----
      f32x4 sc[2][2] = {};
#pragma unroll
      for (int ni = 0; ni < 2; ni++)
#pragma unroll
        for (int dk = 0; dk < 4; dk++) {
          int row = ni * 16 + lo;
          int col = (dk * 32 + hi * 8) ^ ((row & 7) << 3);   // element-index swizzle
          bf16x8 bk_ = *(const bf16x8*)&lK[row * 128 + col];
          sc[0][ni] = MFMA16(aq[0][dk], bk_, sc[0][ni]);
          sc[1][ni] = MFMA16(aq[1][dk], bk_, sc[1][ni]);
        }

      // ---- online softmax per row ----
      unsigned short* lPw = &lP[wave][0];
#pragma unroll
      for (int mi = 0; mi < 2; mi++)
#pragma unroll
        for (int i = 0; i < 4; i++) {
          int qrow = q0 + mi * 16 + hi * 4 + i;
          float s0 = sc[mi][0][i] * scale;
          float s1 = sc[mi][1][i] * scale;
          int kc = kt * 32 + lo;
          if (kc > qrow) s0 = -INFINITY;
          if (kc + 16 > qrow) s1 = -INFINITY;
          float mt = fmaxf(s0, s1);
          mt = fmaxf(mt, __shfl_xor(mt, 1));
          mt = fmaxf(mt, __shfl_xor(mt, 2));
          mt = fmaxf(mt, __shfl_xor(mt, 4));
          mt = fmaxf(mt, __shfl_xor(mt, 8));
          float mo = mrun[mi][i];
          float mn = fmaxf(mo, mt);
          float alpha = __expf(mo - mn);        // exp(-inf)=0 handles first tile
          float p0 = __expf(s0 - mn);
          float p1 = __expf(s1 - mn);
          float rs = p0 + p1;
          rs += __shfl_xor(rs, 1);
          rs += __shfl_xor(rs, 2);
          rs += __shfl_xor(rs, 4);
          rs += __shfl_xor(rs, 8);
          mrun[mi][i] = mn;
          lrun[mi][i] = lrun[mi][i] * alpha + rs;
#pragma unroll
          for (int ni = 0; ni < 8; ni++) acc[mi][ni][i] *= alpha;
          int prow = mi * 16 + hi * 4 + i;
          lPw[prow * 40 + lo] = f2bf(p0);
          lPw[prow * 40 + 16 + lo] = f2bf(p1);
        }

      // ---- PV: O += P[32q x 32k] * V[32k x 128d] ----
      bf16x8 ap0 = *(const bf16x8*)&lPw[(lo) * 40 + hi * 8];
      bf16x8 ap1 = *(const bf16x8*)&lPw[(16 + lo) * 40 + hi * 8];
#pragma unroll
      for (int ni = 0; ni < 8; ni++) {
        bf16x8 bv_ = *(const bf16x8*)&lVt[(ni * 16 + lo) * 40 + hi * 8];
        acc[0][ni] = MFMA16(ap0, bv_, acc[0][ni]);
        acc[1][ni] = MFMA16(ap1, bv_, acc[1][ni]);
      }
    }
  }

  // ---- epilogue: O[b, s, h*128+d] = acc / l ----
  const int b = bh >> 4, hh = bh & 15;
#pragma unroll
  for (int mi = 0; mi < 2; mi++)
#pragma unroll
    for (int i = 0; i < 4; i++) {
      float inv = 1.0f / lrun[mi][i];
      int s = q0 + mi * 16 + hi * 4 + i;
      size_t rowbase = ((size_t)b * 2048 + s) * 2048 + hh * 128 + lo;
#pragma unroll
      for (int ni = 0; ni < 8; ni++)
        Ob[rowbase + ni * 16] = f2bf(acc[mi][ni][i] * inv);
    }
}

// ---------------------------------------------------------------------------
extern "C" void kernel_launch(void* const* d_in, const int* in_sizes, int n_in,
                              void* d_out, int out_size, void* d_ws, size_t ws_size,
                              hipStream_t stream) {
  const float* h  = (const float*)d_in[0];
  const float* Wq = (const float*)d_in[1];
  const float* bq = (const float*)d_in[2];
  const float* Wk = (const float*)d_in[3];
  const float* bk = (const float*)d_in[4];
  const float* Wv = (const float*)d_in[5];
  const float* bv = (const float*)d_in[6];
  const float* Wo = (const float*)d_in[7];
  const float* bo = (const float*)d_in[8];
  float* out = (float*)d_out;

  char* ws = (char*)d_ws;
  unsigned short* h_bf  = (unsigned short*)(ws + 0);            // 32 MiB
  unsigned short* Qb    = (unsigned short*)(ws + 33554432);     // 32 MiB
  unsigned short* Kb    = (unsigned short*)(ws + 67108864);     // 32 MiB
  unsigned short* Vb    = (unsigned short*)(ws + 100663296);    // 32 MiB
  unsigned short* Wqkv  = (unsigned short*)(ws + 134217728);    // 24 MiB
  unsigned short* Wo_bf = (unsigned short*)(ws + 159383552);    // 8 MiB
  unsigned short* Ob    = h_bf;                                 // reuse after QKV GEMM

  // fp32 -> bf16 conversions
  cvt_kernel<<<16384, 256, 0, stream>>>(h, h_bf, 4194304);
  cvt_kernel<<<4096, 256, 0, stream>>>(Wq, Wqkv, 1048576);
  cvt_kernel<<<4096, 256, 0, stream>>>(Wk, Wqkv + 4194304, 1048576);
  cvt_kernel<<<4096, 256, 0, stream>>>(Wv, Wqkv + 8388608, 1048576);
  cvt_kernel<<<4096, 256, 0, stream>>>(Wo, Wo_bf, 1048576);

  // QKV projection (M=8192, N=6144, K=2048)
  gemm_qkv<<<dim3(64 * 48), dim3(256), 0, stream>>>(h_bf, Wqkv, bq, bk, bv, Qb, Kb, Vb);

  // causal attention (64 bh x 16 q-tiles)
  attn_kernel<<<dim3(1024), dim3(256), 0, stream>>>(Qb, Kb, Vb, Ob);

  // output projection (M=8192, N=2048, K=2048), fp32 out
  gemm_out<<<dim3(64 * 16), dim3(256), 0, stream>>>(Ob, Wo_bf, bo, out);
}

// Round 2
// 528.029 us; speedup vs baseline: 1.0573x; 1.0573x over previous
//
#include <hip/hip_runtime.h>
#include <hip/hip_bf16.h>
#include <math.h>

// ---------------------------------------------------------------------------
// GPT2 attention block: out = Attn(h) for B=4, S=2048, H=2048, nh=16, hd=128
// Pipeline (all bf16 MFMA, fp32 accumulate):
//   1) cvt fp32->bf16: h, [Wq;Wk;Wv] (concat), Wo
//   2) gemm_qkv: 256^2-tile 8-phase GEMM -> Q,K,V in [bh][S][128]
//   3) attn: causal flash attention per (bh, 128-row Q tile) -> O bf16
//   4) gemm_out: 256^2-tile 8-phase GEMM O @ Wo^T + bo -> fp32 d_out
// ---------------------------------------------------------------------------

using bf16x8 = __attribute__((ext_vector_type(8))) __bf16;
using f32x4  = __attribute__((ext_vector_type(4))) float;
using s16x8  = __attribute__((ext_vector_type(8))) short;

#define MFMA16(a, b, c) __builtin_amdgcn_mfma_f32_16x16x32_bf16((a), (b), (c), 0, 0, 0)

__device__ __forceinline__ unsigned short f2bf(float f) {
  unsigned u = __float_as_uint(f);
  u += 0x7FFFu + ((u >> 16) & 1u);   // round-to-nearest-even (finite inputs only)
  return (unsigned short)(u >> 16);
}

__device__ __forceinline__ void gload16(const void* g, void* l) {
  __builtin_amdgcn_global_load_lds((const __attribute__((address_space(1))) void*)g,
                                   (__attribute__((address_space(3))) void*)l,
                                   16, 0, 0);
}

// ---------------------------------------------------------------------------
// fp32 -> bf16 convert, 4 elems/thread
// ---------------------------------------------------------------------------
__global__ void cvt_kernel(const float* __restrict__ in, unsigned short* __restrict__ out, int n4) {
  int i = blockIdx.x * 256 + threadIdx.x;
  if (i >= n4) return;
  float4 v = ((const float4*)in)[i];
  ushort4 o;
  o.x = f2bf(v.x); o.y = f2bf(v.y); o.z = f2bf(v.z); o.w = f2bf(v.w);
  ((ushort4*)out)[i] = o;
}

// ---------------------------------------------------------------------------
// 256x256-tile, BK=64, 8-wave (2Mx4N) 8-phase GEMM core (both A and W are
// K-contiguous: C[m,n] = sum_k A[m,k]*W[n,k]).
// LDS: double-buffered A,B tiles [256][64] bf16, XOR-swizzled 16B slots
// (slot ^= row&7) via pre-swizzled global source + linear gload_lds dest.
// Per K-tile: 4 phases (kk,mh); 16 MFMA/phase/wave; all 8 staging loads for
// tile t+1 issued at phase 1 of tile t; single vmcnt(0) at phase 4.
// ---------------------------------------------------------------------------

// staging: thread (wave,lane), j=0..3 covers row j*64+wave*8+(lane>>3), slot lane&7
#define GEMM_PRE()                                                             \
  const int tid = threadIdx.x;                                                 \
  const int wave = tid >> 6, lane = tid & 63;                                  \
  const int lo = lane & 15, hi = lane >> 4;                                    \
  const int wr = wave >> 2, wc = wave & 3;                                     \
  const int rl = lane >> 3, sl = lane & 7;                                     \
  const int sx = ((sl ^ rl) << 3);                                             \
  const unsigned short* aS[4]; const unsigned short* bS[4];                    \
  _Pragma("unroll")                                                            \
  for (int j = 0; j < 4; ++j) {                                                \
    aS[j] = A + (size_t)(m0 + j * 64 + wave * 8 + rl) * 2048 + sx;             \
    bS[j] = W + (size_t)(n0 + j * 64 + wave * 8 + rl) * 2048 + sx;             \
  }                                                                            \
  f32x4 acc[8][4] = {};

#define STAGE(NXT)                                                             \
  do {                                                                         \
    _Pragma("unroll")                                                          \
    for (int j = 0; j < 4; ++j) {                                              \
      gload16(aS[j], &lA[NXT][j * 4096 + wave * 512]);                         \
      gload16(bS[j], &lB[NXT][j * 4096 + wave * 512]);                         \
      aS[j] += 64; bS[j] += 64;                                                \
    }                                                                          \
  } while (0)

#define LDA4(dst, MH, KK, CUR)                                                 \
  do {                                                                         \
    _Pragma("unroll")                                                          \
    for (int im = 0; im < 4; ++im)                                             \
      dst[im] = *(const bf16x8*)&lA[CUR][(wr * 128 + ((MH)*4 + im) * 16 + lo) * 64 + \
                                         ((((KK)*4 + hi) ^ (lo & 7)) << 3)];   \
  } while (0)

#define LDB4(dst, KK, CUR)                                                     \
  do {                                                                         \
    _Pragma("unroll")                                                          \
    for (int ni = 0; ni < 4; ++ni)                                             \
      dst[ni] = *(const bf16x8*)&lB[CUR][(wc * 64 + ni * 16 + lo) * 64 +       \
                                         ((((KK)*4 + hi) ^ (lo & 7)) << 3)];   \
  } while (0)

#define MF16(MH, aF, bF)                                                       \
  do {                                                                         \
    __builtin_amdgcn_s_setprio(1);                                             \
    _Pragma("unroll")                                                          \
    for (int im = 0; im < 4; ++im)                                             \
      _Pragma("unroll")                                                        \
      for (int ni = 0; ni < 4; ++ni)                                           \
        acc[(MH)*4 + im][ni] = MFMA16(aF[im], bF[ni], acc[(MH)*4 + im][ni]);   \
    __builtin_amdgcn_s_setprio(0);                                             \
  } while (0)

#define BAR __builtin_amdgcn_s_barrier()
#define VMW asm volatile("s_waitcnt vmcnt(0)" ::: "memory")

#define GEMM_TILE(CUR, NXT, COND)                                              \
  do {                                                                         \
    bf16x8 aF[4], bF0[4], bF1[4];                                              \
    /* phase 1: (kk0, mh0) + stage next tile */                                \
    LDA4(aF, 0, 0, CUR); LDB4(bF0, 0, CUR);                                    \
    if (COND) STAGE(NXT);                                                      \
    BAR; MF16(0, aF, bF0); BAR;                                                \
    /* phase 2: (kk0, mh1) */                                                  \
    LDA4(aF, 1, 0, CUR);                                                       \
    BAR; MF16(1, aF, bF0); BAR;                                                \
    /* phase 3: (kk1, mh0) */                                                  \
    LDA4(aF, 0, 1, CUR); LDB4(bF1, 1, CUR);                                    \
    BAR; MF16(0, aF, bF1); BAR;                                                \
    /* phase 4: (kk1, mh1), wait for next tile's staging before last barrier */\
    LDA4(aF, 1, 1, CUR);                                                       \
    VMW; BAR; MF16(1, aF, bF1); BAR;                                           \
  } while (0)

#define GEMM_MAIN()                                                            \
  STAGE(0);                                                                    \
  VMW; BAR;                                                                    \
  for (int t = 0; t < 32; t += 2) {                                            \
    GEMM_TILE(0, 1, true);                                                     \
    GEMM_TILE(1, 0, (t + 2 < 32));                                             \
  }

// ---------------------------------------------------------------------------
// QKV GEMM: M=8192 (B*S), N=6144 (Wq;Wk;Wv), K=2048. Output scattered into
// Q/K/V [b,nh,S,hd] bf16 with bias.
// ---------------------------------------------------------------------------
__global__ __launch_bounds__(512, 2)
void gemm_qkv(const unsigned short* __restrict__ A,
              const unsigned short* __restrict__ W,
              const float* __restrict__ bq, const float* __restrict__ bk,
              const float* __restrict__ bv,
              unsigned short* __restrict__ Q, unsigned short* __restrict__ Kq,
              unsigned short* __restrict__ V) {
  __shared__ unsigned short lA[2][256 * 64];
  __shared__ unsigned short lB[2][256 * 64];
  // XCD swizzle (768 blocks, 96/XCD), bm-major within chunk for A-panel reuse
  const int bid = blockIdx.x;
  const int sid = (bid & 7) * 96 + (bid >> 3);
  const int bm = sid / 24, bn = sid % 24;
  const int m0 = bm * 256, n0 = bn * 256;
  GEMM_PRE();
  GEMM_MAIN();

  // epilogue: which of Q/K/V is uniform per block (2048 % 256 == 0)
  const int which = n0 >> 11;
  const float* bias = (which == 0) ? bq : (which == 1) ? bk : bv;
  unsigned short* dst = (which == 0) ? Q : (which == 1) ? Kq : V;
#pragma unroll
  for (int mi = 0; mi < 8; mi++)
#pragma unroll
    for (int ni = 0; ni < 4; ni++) {
      int n_g = n0 + wc * 64 + ni * 16 + lo;
      int n2 = n_g & 2047;
      int head = n2 >> 7, d = n2 & 127;
      float bb = bias[n2];
#pragma unroll
      for (int i = 0; i < 4; i++) {
        int m = m0 + wr * 128 + mi * 16 + hi * 4 + i;
        int b = m >> 11, s = m & 2047;
        dst[(((size_t)b * 16 + head) * 2048 + s) * 128 + d] = f2bf(acc[mi][ni][i] + bb);
      }
    }
}

// ---------------------------------------------------------------------------
// Output GEMM: M=8192, N=2048, K=2048, fp32 out + bias.
// ---------------------------------------------------------------------------
__global__ __launch_bounds__(512, 2)
void gemm_out(const unsigned short* __restrict__ A,
              const unsigned short* __restrict__ W,
              const float* __restrict__ bo, float* __restrict__ out) {
  __shared__ unsigned short lA[2][256 * 64];
  __shared__ unsigned short lB[2][256 * 64];
  // XCD swizzle (256 blocks, 32/XCD), bm-major within chunk
  const int bid = blockIdx.x;
  const int sid = (bid & 7) * 32 + (bid >> 3);
  const int bm = sid >> 3, bn = sid & 7;
  const int m0 = bm * 256, n0 = bn * 256;
  GEMM_PRE();
  GEMM_MAIN();

#pragma unroll
  for (int mi = 0; mi < 8; mi++)
#pragma unroll
    for (int ni = 0; ni < 4; ni++) {
      int n_g = n0 + wc * 64 + ni * 16 + lo;
      float bb = bo[n_g];
#pragma unroll
      for (int i = 0; i < 4; i++) {
        int m = m0 + wr * 128 + mi * 16 + hi * 4 + i;
        out[(size_t)m * 2048 + n_g] = acc[mi][ni][i] + bb;
      }
    }
}

// ---------------------------------------------------------------------------
// Causal flash attention. Grid: 64 (bh) x 16 (q-tiles of 128). 4 waves/block,
// wave w owns rows q0 = qt*128 + w*32 .. +31 (2 m-frags of 16).
// K-tile (32 keys) staged in LDS with XOR swizzle (byte ^= (row&7)<<4) via
// pre-swizzled global_load_lds source; V staged transposed into padded LDS.
// ---------------------------------------------------------------------------
__global__ __launch_bounds__(256, 2)
void attn_kernel(const unsigned short* __restrict__ Qb,
                 const unsigned short* __restrict__ Kb,
                 const unsigned short* __restrict__ Vb,
                 unsigned short* __restrict__ Ob) {
  __shared__ unsigned short lK[32 * 128];       // swizzled row-major [32][128]
  __shared__ unsigned short lVt[128 * 40];      // V^T [128 d][32 k], pad to 40
  __shared__ unsigned short lP[4][32 * 40];     // per-wave P tile [32 q][32 k], pad 40

  const int tid = threadIdx.x;
  const int wave = tid >> 6, lane = tid & 63;
  const int lo = lane & 15, hi = lane >> 4;
  const int bh = blockIdx.x & 63;
  const int qt = 15 - (blockIdx.x >> 6);        // heavy tiles dispatched first
  const int q0 = qt * 128 + wave * 32;
  const size_t base = (size_t)bh * 2048 * 128;
  const float scale = 0.08838834764831845f;     // 1/sqrt(128)

  // Q fragments in registers: rows q0+mi*16+lo, d = dk*32 + hi*8 ..+7
  bf16x8 aq[2][4];
#pragma unroll
  for (int mi = 0; mi < 2; mi++)
#pragma unroll
    for (int dk = 0; dk < 4; dk++)
      aq[mi][dk] = *(const bf16x8*)&Qb[base + (size_t)(q0 + mi * 16 + lo) * 128 + dk * 32 + hi * 8];

  f32x4 acc[2][8] = {};
  float mrun[2][4], lrun[2][4];
#pragma unroll
  for (int a = 0; a < 2; a++)
#pragma unroll
    for (int b = 0; b < 4; b++) { mrun[a][b] = -INFINITY; lrun[a][b] = 0.0f; }

  const int ktn = qt * 4 + 4;                   // tiles covering k <= q0_block+127
  const int qmax_w = q0 + 31;

  for (int kt = 0; kt < ktn; kt++) {
    __syncthreads();
    // ---- stage K tile (swizzled source -> linear LDS dest) ----
#pragma unroll
    for (int j = 0; j < 2; j++) {
      int c = wave * 2 + j;
      int row = c * 4 + hi;                                  // 0..31
      int srccol = (lo * 16) ^ ((row & 7) << 4);             // byte offset in 256B row
      const unsigned short* g = Kb + base + (size_t)(kt * 32 + row) * 128 + (srccol >> 1);
      gload16(g, &lK[c * 512]);
    }
    // ---- stage V transposed: thread -> rows {2rr,2rr+1}, cols c0..c0+7 ----
    {
      int rr = tid & 15;
      int c0 = (tid >> 4) * 8;
      const unsigned short* vp = Vb + base + (size_t)(kt * 32 + 2 * rr) * 128 + c0;
      s16x8 va = *(const s16x8*)vp;
      s16x8 vb2 = *(const s16x8*)(vp + 128);
#pragma unroll
      for (int j = 0; j < 8; j++)
        *(ushort2*)&lVt[(c0 + j) * 40 + 2 * rr] =
            make_ushort2((unsigned short)va[j], (unsigned short)vb2[j]);
    }
    __syncthreads();

    if (kt * 32 <= qmax_w) {                    // wave-uniform: tile not fully masked
      // ---- scores: S[32q][32k] ----
      f32x4 sc[2][2] = {};
#pragma unroll
      for (int ni = 0; ni < 2; ni++)
#pragma unroll
        for (int dk = 0; dk < 4; dk++) {
          int row = ni * 16 + lo;
          int col = (dk * 32 + hi * 8) ^ ((row & 7) << 3);   // element-index swizzle
          bf16x8 bk_ = *(const bf16x8*)&lK[row * 128 + col];
          sc[0][ni] = MFMA16(aq[0][dk], bk_, sc[0][ni]);
          sc[1][ni] = MFMA16(aq[1][dk], bk_, sc[1][ni]);
        }

      // ---- online softmax per row ----
      unsigned short* lPw = &lP[wave][0];
#pragma unroll
      for (int mi = 0; mi < 2; mi++)
#pragma unroll
        for (int i = 0; i < 4; i++) {
          int qrow = q0 + mi * 16 + hi * 4 + i;
          float s0 = sc[mi][0][i] * scale;
          float s1 = sc[mi][1][i] * scale;
          int kc = kt * 32 + lo;
          if (kc > qrow) s0 = -INFINITY;
          if (kc + 16 > qrow) s1 = -INFINITY;
          float mt = fmaxf(s0, s1);
          mt = fmaxf(mt, __shfl_xor(mt, 1));
          mt = fmaxf(mt, __shfl_xor(mt, 2));
          mt = fmaxf(mt, __shfl_xor(mt, 4));
          mt = fmaxf(mt, __shfl_xor(mt, 8));
          float mo = mrun[mi][i];
          float mn = fmaxf(mo, mt);
          float alpha = __expf(mo - mn);        // exp(-inf)=0 handles first tile
          float p0 = __expf(s0 - mn);
          float p1 = __expf(s1 - mn);
          float rs = p0 + p1;
          rs += __shfl_xor(rs, 1);
          rs += __shfl_xor(rs, 2);
          rs += __shfl_xor(rs, 4);
          rs += __shfl_xor(rs, 8);
          mrun[mi][i] = mn;
          lrun[mi][i] = lrun[mi][i] * alpha + rs;
#pragma unroll
          for (int ni = 0; ni < 8; ni++) acc[mi][ni][i] *= alpha;
          int prow = mi * 16 + hi * 4 + i;
          lPw[prow * 40 + lo] = f2bf(p0);
          lPw[prow * 40 + 16 + lo] = f2bf(p1);
        }

      // ---- PV: O += P[32q x 32k] * V[32k x 128d] ----
      bf16x8 ap0 = *(const bf16x8*)&lPw[(lo) * 40 + hi * 8];
      bf16x8 ap1 = *(const bf16x8*)&lPw[(16 + lo) * 40 + hi * 8];
#pragma unroll
      for (int ni = 0; ni < 8; ni++) {
        bf16x8 bv_ = *(const bf16x8*)&lVt[(ni * 16 + lo) * 40 + hi * 8];
        acc[0][ni] = MFMA16(ap0, bv_, acc[0][ni]);
        acc[1][ni] = MFMA16(ap1, bv_, acc[1][ni]);
      }
    }
  }

  // ---- epilogue: O[b, s, h*128+d] = acc / l ----
  const int b = bh >> 4, hh = bh & 15;
#pragma unroll
  for (int mi = 0; mi < 2; mi++)
#pragma unroll
    for (int i = 0; i < 4; i++) {
      float inv = 1.0f / lrun[mi][i];
      int s = q0 + mi * 16 + hi * 4 + i;
      size_t rowbase = ((size_t)b * 2048 + s) * 2048 + hh * 128 + lo;
#pragma unroll
      for (int ni = 0; ni < 8; ni++)
        Ob[rowbase + ni * 16] = f2bf(acc[mi][ni][i] * inv);
    }
}

// ---------------------------------------------------------------------------
extern "C" void kernel_launch(void* const* d_in, const int* in_sizes, int n_in,
                              void* d_out, int out_size, void* d_ws, size_t ws_size,
                              hipStream_t stream) {
  const float* h  = (const float*)d_in[0];
  const float* Wq = (const float*)d_in[1];
  const float* bq = (const float*)d_in[2];
  const float* Wk = (const float*)d_in[3];
  const float* bk = (const float*)d_in[4];
  const float* Wv = (const float*)d_in[5];
  const float* bv = (const float*)d_in[6];
  const float* Wo = (const float*)d_in[7];
  const float* bo = (const float*)d_in[8];
  float* out = (float*)d_out;

  char* ws = (char*)d_ws;
  unsigned short* h_bf  = (unsigned short*)(ws + 0);            // 32 MiB
  unsigned short* Qb    = (unsigned short*)(ws + 33554432);     // 32 MiB
  unsigned short* Kb    = (unsigned short*)(ws + 67108864);     // 32 MiB
  unsigned short* Vb    = (unsigned short*)(ws + 100663296);    // 32 MiB
  unsigned short* Wqkv  = (unsigned short*)(ws + 134217728);    // 24 MiB
  unsigned short* Wo_bf = (unsigned short*)(ws + 159383552);    // 8 MiB
  unsigned short* Ob    = h_bf;                                 // reuse after QKV GEMM

  // fp32 -> bf16 conversions
  cvt_kernel<<<16384, 256, 0, stream>>>(h, h_bf, 4194304);
  cvt_kernel<<<4096, 256, 0, stream>>>(Wq, Wqkv, 1048576);
  cvt_kernel<<<4096, 256, 0, stream>>>(Wk, Wqkv + 4194304, 1048576);
  cvt_kernel<<<4096, 256, 0, stream>>>(Wv, Wqkv + 8388608, 1048576);
  cvt_kernel<<<4096, 256, 0, stream>>>(Wo, Wo_bf, 1048576);

  // QKV projection (M=8192, N=6144, K=2048), 32x24 blocks of 256x256
  gemm_qkv<<<dim3(768), dim3(512), 0, stream>>>(h_bf, Wqkv, bq, bk, bv, Qb, Kb, Vb);

  // causal attention (64 bh x 16 q-tiles)
  attn_kernel<<<dim3(1024), dim3(256), 0, stream>>>(Qb, Kb, Vb, Ob);

  // output projection (M=8192, N=2048, K=2048), 32x8 blocks, fp32 out
  gemm_out<<<dim3(256), dim3(512), 0, stream>>>(Ob, Wo_bf, bo, out);
}

// Round 4
// 515.999 us; speedup vs baseline: 1.0819x; 1.0233x over previous
//
#include <hip/hip_runtime.h>
#include <hip/hip_bf16.h>
#include <math.h>

// ---------------------------------------------------------------------------
// GPT2 attention block: out = Attn(h) for B=4, S=2048, H=2048, nh=16, hd=128
// Pipeline (all bf16 MFMA, fp32 accumulate):
//   1) cvt fp32->bf16: h, [Wq;Wk;Wv] (concat), Wo
//   2) gemm_qkv: 256^2-tile GEMM (BK=32, 4-buf, stage-ahead-3, vmcnt(8))
//   3) attn: causal flash attention per (bh, 128-row Q tile) -> O bf16
//   4) gemm_out: same GEMM core, O @ Wo^T + bo -> fp32 d_out
// ---------------------------------------------------------------------------

using bf16x8 = __attribute__((ext_vector_type(8))) __bf16;
using f32x4  = __attribute__((ext_vector_type(4))) float;
using s16x8  = __attribute__((ext_vector_type(8))) short;

#define MFMA16(a, b, c) __builtin_amdgcn_mfma_f32_16x16x32_bf16((a), (b), (c), 0, 0, 0)

__device__ __forceinline__ unsigned short f2bf(float f) {
  unsigned u = __float_as_uint(f);
  u += 0x7FFFu + ((u >> 16) & 1u);   // round-to-nearest-even (finite inputs only)
  return (unsigned short)(u >> 16);
}

__device__ __forceinline__ void gload16(const void* g, void* l) {
  __builtin_amdgcn_global_load_lds((const __attribute__((address_space(1))) void*)g,
                                   (__attribute__((address_space(3))) void*)l,
                                   16, 0, 0);
}

// ---------------------------------------------------------------------------
// fp32 -> bf16 convert, 4 elems/thread
// ---------------------------------------------------------------------------
__global__ void cvt_kernel(const float* __restrict__ in, unsigned short* __restrict__ out, int n4) {
  int i = blockIdx.x * 256 + threadIdx.x;
  if (i >= n4) return;
  float4 v = ((const float4*)in)[i];
  ushort4 o;
  o.x = f2bf(v.x); o.y = f2bf(v.y); o.z = f2bf(v.z); o.w = f2bf(v.w);
  ((ushort4*)out)[i] = o;
}

// ---------------------------------------------------------------------------
// 256x256-tile, BK=32, 8-wave (2Mx4N) GEMM core, counted-vmcnt pipeline.
// Both operands K-contiguous: C[m,n] = sum_k A[m,k]*W[n,k]. 64 K-tiles.
// LDS: 4 buffers x (A[256][32] + B[256][32]) bf16 = 128 KiB.
// Tile t reads buf t%4 and stages tile t+3 into buf (t+3)%4 — that buffer
// held tile t-1, fully consumed before tile t-1's closing barrier, so the
// stage (issued after that barrier) can never race a reader. Since
// t+1..t+3 != t (mod 4), no stage touches the buffer being read.
// Steady-state wait: vmcnt(8) at tile end (loads from t-1,t in flight; loads
// for t+1 issued at t-2 must be done). Tail uses vmcnt 8/4/0 explicitly —
// with <8 loads in flight a uniform vmcnt(8) is a no-op and would race.
// 16B slots XOR-swizzled (slot ^= row&3): pre-swizzled global source +
// linear gload_lds dest + swizzled ds_read (both-sides, rule #21).
// ---------------------------------------------------------------------------

#define GEMM_PRE()                                                             \
  const int tid = threadIdx.x;                                                 \
  const int wave = tid >> 6, lane = tid & 63;                                  \
  const int lo = lane & 15, hi = lane >> 4;                                    \
  const int wr = wave >> 2, wc = wave & 3;                                     \
  const int r4 = lane >> 2, s4 = lane & 3;                                     \
  const int scol = ((s4 ^ (r4 & 3)) << 3);                                     \
  const unsigned short* aS[2]; const unsigned short* bS[2];                    \
  _Pragma("unroll")                                                            \
  for (int j = 0; j < 2; ++j) {                                                \
    aS[j] = A + (size_t)(m0 + (wave * 2 + j) * 16 + r4) * 2048 + scol;         \
    bS[j] = W + (size_t)(n0 + (wave * 2 + j) * 16 + r4) * 2048 + scol;         \
  }                                                                            \
  f32x4 acc[8][4] = {};

// stage row-block (wave*2+J)*16 of A and B (next unstaged K-tile) into BUF
#define STAGE2(BUF, J)                                                         \
  do {                                                                         \
    gload16(aS[J], &lA[BUF][(wave * 2 + (J)) * 512]);                          \
    gload16(bS[J], &lB[BUF][(wave * 2 + (J)) * 512]);                          \
    aS[J] += 32; bS[J] += 32;                                                  \
  } while (0)

#define LDA4_(dst, MH, BUF)                                                    \
  do {                                                                         \
    _Pragma("unroll")                                                          \
    for (int im = 0; im < 4; ++im)                                             \
      dst[im] = *(const bf16x8*)&lA[BUF][(wr * 128 + (MH)*64 + im * 16 + lo) * 32 + \
                                         ((hi ^ (lo & 3)) << 3)];              \
  } while (0)

#define LDB4_(dst, BUF)                                                        \
  do {                                                                         \
    _Pragma("unroll")                                                          \
    for (int ni = 0; ni < 4; ++ni)                                             \
      dst[ni] = *(const bf16x8*)&lB[BUF][(wc * 64 + ni * 16 + lo) * 32 +       \
                                         ((hi ^ (lo & 3)) << 3)];              \
  } while (0)

#define MF16(MH, aF, bF)                                                       \
  do {                                                                         \
    __builtin_amdgcn_s_setprio(1);                                             \
    _Pragma("unroll")                                                          \
    for (int im = 0; im < 4; ++im)                                             \
      _Pragma("unroll")                                                        \
      for (int ni = 0; ni < 4; ++ni)                                           \
        acc[(MH)*4 + im][ni] = MFMA16(aF[im], bF[ni], acc[(MH)*4 + im][ni]);   \
    __builtin_amdgcn_s_setprio(0);                                             \
  } while (0)

#define BAR __builtin_amdgcn_s_barrier()
#define VMC(N) asm volatile("s_waitcnt vmcnt(" #N ")" ::: "memory")

// one K-tile: 2 phases; reads RBUF, stages the next unstaged tile into SBUF,
// trailing wait vmcnt(VN) guarantees the NEXT tile's buffer is fully staged
#define TILE(RBUF, SBUF, COND, VN)                                             \
  do {                                                                         \
    bf16x8 aF[4], aG[4], bF[4];                                                \
    LDA4_(aF, 0, RBUF); LDB4_(bF, RBUF);                                       \
    if (COND) STAGE2(SBUF, 0);                                                 \
    BAR; MF16(0, aF, bF); BAR;                                                 \
    LDA4_(aG, 1, RBUF);                                                        \
    if (COND) STAGE2(SBUF, 1);                                                 \
    BAR; MF16(1, aG, bF); VMC(VN); BAR;                                        \
  } while (0)

#define GEMM_MAIN()                                                            \
  STAGE2(0, 0); STAGE2(0, 1); STAGE2(1, 0); STAGE2(1, 1);                      \
  STAGE2(2, 0); STAGE2(2, 1);                                                  \
  VMC(8); BAR;                                                                 \
  for (int u = 0; u < 15; ++u) {                                               \
    TILE(0, 3, true, 8); TILE(1, 0, true, 8);                                  \
    TILE(2, 1, true, 8); TILE(3, 2, true, 8);                                  \
  }                                                                            \
  /* tiles 60..63: stage only t=60 (tile 63); tail waits 8/4/0/0 */            \
  TILE(0, 3, true, 8); TILE(1, 0, false, 4);                                   \
  TILE(2, 1, false, 0); TILE(3, 2, false, 0);

// ---------------------------------------------------------------------------
// QKV GEMM: M=8192 (B*S), N=6144 (Wq;Wk;Wv), K=2048. Output scattered into
// Q/K/V [b,nh,S,hd] bf16 with bias.
// ---------------------------------------------------------------------------
__global__ __launch_bounds__(512, 2)
void gemm_qkv(const unsigned short* __restrict__ A,
              const unsigned short* __restrict__ W,
              const float* __restrict__ bq, const float* __restrict__ bk,
              const float* __restrict__ bv,
              unsigned short* __restrict__ Q, unsigned short* __restrict__ Kq,
              unsigned short* __restrict__ V) {
  __shared__ unsigned short lA[4][256 * 32];
  __shared__ unsigned short lB[4][256 * 32];
  // XCD swizzle (768 blocks, 96/XCD), bn-fast within chunk
  const int bid = blockIdx.x;
  const int sid = (bid & 7) * 96 + (bid >> 3);
  const int bm = sid / 24, bn = sid % 24;
  const int m0 = bm * 256, n0 = bn * 256;
  GEMM_PRE();
  GEMM_MAIN();

  // epilogue: which of Q/K/V is uniform per block (2048 % 256 == 0)
  const int which = n0 >> 11;
  const float* bias = (which == 0) ? bq : (which == 1) ? bk : bv;
  unsigned short* dst = (which == 0) ? Q : (which == 1) ? Kq : V;
#pragma unroll
  for (int mi = 0; mi < 8; mi++)
#pragma unroll
    for (int ni = 0; ni < 4; ni++) {
      int n_g = n0 + wc * 64 + ni * 16 + lo;
      int n2 = n_g & 2047;
      int head = n2 >> 7, d = n2 & 127;
      float bb = bias[n2];
#pragma unroll
      for (int i = 0; i < 4; i++) {
        int m = m0 + wr * 128 + mi * 16 + hi * 4 + i;
        int b = m >> 11, s = m & 2047;
        dst[(((size_t)b * 16 + head) * 2048 + s) * 128 + d] = f2bf(acc[mi][ni][i] + bb);
      }
    }
}

// ---------------------------------------------------------------------------
// Output GEMM: M=8192, N=2048, K=2048, fp32 out + bias.
// ---------------------------------------------------------------------------
__global__ __launch_bounds__(512, 2)
void gemm_out(const unsigned short* __restrict__ A,
              const unsigned short* __restrict__ W,
              const float* __restrict__ bo, float* __restrict__ out) {
  __shared__ unsigned short lA[4][256 * 32];
  __shared__ unsigned short lB[4][256 * 32];
  // XCD swizzle (256 blocks, 32/XCD)
  const int bid = blockIdx.x;
  const int sid = (bid & 7) * 32 + (bid >> 3);
  const int bm = sid >> 3, bn = sid & 7;
  const int m0 = bm * 256, n0 = bn * 256;
  GEMM_PRE();
  GEMM_MAIN();

#pragma unroll
  for (int mi = 0; mi < 8; mi++)
#pragma unroll
    for (int ni = 0; ni < 4; ni++) {
      int n_g = n0 + wc * 64 + ni * 16 + lo;
      float bb = bo[n_g];
#pragma unroll
      for (int i = 0; i < 4; i++) {
        int m = m0 + wr * 128 + mi * 16 + hi * 4 + i;
        out[(size_t)m * 2048 + n_g] = acc[mi][ni][i] + bb;
      }
    }
}

// ---------------------------------------------------------------------------
// Causal flash attention. Grid: 64 (bh) x 16 (q-tiles of 128). 4 waves/block,
// wave w owns rows q0 = qt*128 + w*32 .. +31 (2 m-frags of 16).
// K-tile (32 keys) staged in LDS with XOR swizzle (byte ^= (row&7)<<4) via
// pre-swizzled global_load_lds source; V staged transposed into padded LDS.
// ---------------------------------------------------------------------------
__global__ __launch_bounds__(256, 2)
void attn_kernel(const unsigned short* __restrict__ Qb,
                 const unsigned short* __restrict__ Kb,
                 const unsigned short* __restrict__ Vb,
                 unsigned short* __restrict__ Ob) {
  __shared__ unsigned short lK[32 * 128];       // swizzled row-major [32][128]
  __shared__ unsigned short lVt[128 * 40];      // V^T [128 d][32 k], pad to 40
  __shared__ unsigned short lP[4][32 * 40];     // per-wave P tile [32 q][32 k], pad 40

  const int tid = threadIdx.x;
  const int wave = tid >> 6, lane = tid & 63;
  const int lo = lane & 15, hi = lane >> 4;
  const int bh = blockIdx.x & 63;
  const int qt = 15 - (blockIdx.x >> 6);        // heavy tiles dispatched first
  const int q0 = qt * 128 + wave * 32;
  const size_t base = (size_t)bh * 2048 * 128;
  const float scale = 0.08838834764831845f;     // 1/sqrt(128)

  // Q fragments in registers: rows q0+mi*16+lo, d = dk*32 + hi*8 ..+7
  bf16x8 aq[2][4];
#pragma unroll
  for (int mi = 0; mi < 2; mi++)
#pragma unroll
    for (int dk = 0; dk < 4; dk++)
      aq[mi][dk] = *(const bf16x8*)&Qb[base + (size_t)(q0 + mi * 16 + lo) * 128 + dk * 32 + hi * 8];

  f32x4 acc[2][8] = {};
  float mrun[2][4], lrun[2][4];
#pragma unroll
  for (int a = 0; a < 2; a++)
#pragma unroll
    for (int b = 0; b < 4; b++) { mrun[a][b] = -INFINITY; lrun[a][b] = 0.0f; }

  const int ktn = qt * 4 + 4;                   // tiles covering k <= q0_block+127
  const int qmax_w = q0 + 31;

  for (int kt = 0; kt < ktn; kt++) {
    __syncthreads();
    // ---- stage K tile (swizzled source -> linear LDS dest) ----
#pragma unroll
    for (int j = 0; j < 2; j++) {
      int c = wave * 2 + j;
      int row = c * 4 + hi;                                  // 0..31
      int srccol = (lo * 16) ^ ((row & 7) << 4);             // byte offset in 256B row
      const unsigned short* g = Kb + base + (size_t)(kt * 32 + row) * 128 + (srccol >> 1);
      gload16(g, &lK[c * 512]);
    }
    // ---- stage V transposed: thread -> rows {2rr,2rr+1}, cols c0..c0+7 ----
    {
      int rr = tid & 15;
      int c0 = (tid >> 4) * 8;
      const unsigned short* vp = Vb + base + (size_t)(kt * 32 + 2 * rr) * 128 + c0;
      s16x8 va = *(const s16x8*)vp;
      s16x8 vb2 = *(const s16x8*)(vp + 128);
#pragma unroll
      for (int j = 0; j < 8; j++)
        *(ushort2*)&lVt[(c0 + j) * 40 + 2 * rr] =
            make_ushort2((unsigned short)va[j], (unsigned short)vb2[j]);
    }
    __syncthreads();

    if (kt * 32 <= qmax_w) {                    // wave-uniform: tile not fully masked
      // ---- scores: S[32q][32k] ----
      f32x4 sc[2][2] = {};
#pragma unroll
      for (int ni = 0; ni < 2; ni++)
#pragma unroll
        for (int dk = 0; dk < 4; dk++) {
          int row = ni * 16 + lo;
          int col = (dk * 32 + hi * 8) ^ ((row & 7) << 3);   // element-index swizzle
          bf16x8 bk_ = *(const bf16x8*)&lK[row * 128 + col];
          sc[0][ni] = MFMA16(aq[0][dk], bk_, sc[0][ni]);
          sc[1][ni] = MFMA16(aq[1][dk], bk_, sc[1][ni]);
        }

      // ---- online softmax per row ----
      unsigned short* lPw = &lP[wave][0];
#pragma unroll
      for (int mi = 0; mi < 2; mi++)
#pragma unroll
        for (int i = 0; i < 4; i++) {
          int qrow = q0 + mi * 16 + hi * 4 + i;
          float s0 = sc[mi][0][i] * scale;
          float s1 = sc[mi][1][i] * scale;
          int kc = kt * 32 + lo;
          if (kc > qrow) s0 = -INFINITY;
          if (kc + 16 > qrow) s1 = -INFINITY;
          float mt = fmaxf(s0, s1);
          mt = fmaxf(mt, __shfl_xor(mt, 1));
          mt = fmaxf(mt, __shfl_xor(mt, 2));
          mt = fmaxf(mt, __shfl_xor(mt, 4));
          mt = fmaxf(mt, __shfl_xor(mt, 8));
          float mo = mrun[mi][i];
          float mn = fmaxf(mo, mt);
          float alpha = __expf(mo - mn);        // exp(-inf)=0 handles first tile
          float p0 = __expf(s0 - mn);
          float p1 = __expf(s1 - mn);
          float rs = p0 + p1;
          rs += __shfl_xor(rs, 1);
          rs += __shfl_xor(rs, 2);
          rs += __shfl_xor(rs, 4);
          rs += __shfl_xor(rs, 8);
          mrun[mi][i] = mn;
          lrun[mi][i] = lrun[mi][i] * alpha + rs;
#pragma unroll
          for (int ni = 0; ni < 8; ni++) acc[mi][ni][i] *= alpha;
          int prow = mi * 16 + hi * 4 + i;
          lPw[prow * 40 + lo] = f2bf(p0);
          lPw[prow * 40 + 16 + lo] = f2bf(p1);
        }

      // ---- PV: O += P[32q x 32k] * V[32k x 128d] ----
      bf16x8 ap0 = *(const bf16x8*)&lPw[(lo) * 40 + hi * 8];
      bf16x8 ap1 = *(const bf16x8*)&lPw[(16 + lo) * 40 + hi * 8];
#pragma unroll
      for (int ni = 0; ni < 8; ni++) {
        bf16x8 bv_ = *(const bf16x8*)&lVt[(ni * 16 + lo) * 40 + hi * 8];
        acc[0][ni] = MFMA16(ap0, bv_, acc[0][ni]);
        acc[1][ni] = MFMA16(ap1, bv_, acc[1][ni]);
      }
    }
  }

  // ---- epilogue: O[b, s, h*128+d] = acc / l ----
  const int b = bh >> 4, hh = bh & 15;
#pragma unroll
  for (int mi = 0; mi < 2; mi++)
#pragma unroll
    for (int i = 0; i < 4; i++) {
      float inv = 1.0f / lrun[mi][i];
      int s = q0 + mi * 16 + hi * 4 + i;
      size_t rowbase = ((size_t)b * 2048 + s) * 2048 + hh * 128 + lo;
#pragma unroll
      for (int ni = 0; ni < 8; ni++)
        Ob[rowbase + ni * 16] = f2bf(acc[mi][ni][i] * inv);
    }
}

// ---------------------------------------------------------------------------
extern "C" void kernel_launch(void* const* d_in, const int* in_sizes, int n_in,
                              void* d_out, int out_size, void* d_ws, size_t ws_size,
                              hipStream_t stream) {
  const float* h  = (const float*)d_in[0];
  const float* Wq = (const float*)d_in[1];
  const float* bq = (const float*)d_in[2];
  const float* Wk = (const float*)d_in[3];
  const float* bk = (const float*)d_in[4];
  const float* Wv = (const float*)d_in[5];
  const float* bv = (const float*)d_in[6];
  const float* Wo = (const float*)d_in[7];
  const float* bo = (const float*)d_in[8];
  float* out = (float*)d_out;

  char* ws = (char*)d_ws;
  unsigned short* h_bf  = (unsigned short*)(ws + 0);            // 32 MiB
  unsigned short* Qb    = (unsigned short*)(ws + 33554432);     // 32 MiB
  unsigned short* Kb    = (unsigned short*)(ws + 67108864);     // 32 MiB
  unsigned short* Vb    = (unsigned short*)(ws + 100663296);    // 32 MiB
  unsigned short* Wqkv  = (unsigned short*)(ws + 134217728);    // 24 MiB
  unsigned short* Wo_bf = (unsigned short*)(ws + 159383552);    // 8 MiB
  unsigned short* Ob    = h_bf;                                 // reuse after QKV GEMM

  // fp32 -> bf16 conversions
  cvt_kernel<<<16384, 256, 0, stream>>>(h, h_bf, 4194304);
  cvt_kernel<<<4096, 256, 0, stream>>>(Wq, Wqkv, 1048576);
  cvt_kernel<<<4096, 256, 0, stream>>>(Wk, Wqkv + 4194304, 1048576);
  cvt_kernel<<<4096, 256, 0, stream>>>(Wv, Wqkv + 8388608, 1048576);
  cvt_kernel<<<4096, 256, 0, stream>>>(Wo, Wo_bf, 1048576);

  // QKV projection (M=8192, N=6144, K=2048), 32x24 blocks of 256x256
  gemm_qkv<<<dim3(768), dim3(512), 0, stream>>>(h_bf, Wqkv, bq, bk, bv, Qb, Kb, Vb);

  // causal attention (64 bh x 16 q-tiles)
  attn_kernel<<<dim3(1024), dim3(256), 0, stream>>>(Qb, Kb, Vb, Ob);

  // output projection (M=8192, N=2048, K=2048), 32x8 blocks, fp32 out
  gemm_out<<<dim3(256), dim3(512), 0, stream>>>(Ob, Wo_bf, bo, out);
}

// Round 5
// 467.994 us; speedup vs baseline: 1.1929x; 1.1026x over previous
//
#include <hip/hip_runtime.h>
#include <hip/hip_bf16.h>
#include <math.h>

// ---------------------------------------------------------------------------
// GPT2 attention block: out = Attn(h) for B=4, S=2048, H=2048, nh=16, hd=128
// Pipeline (all bf16 MFMA, fp32 accumulate):
//   1) cvt fp32->bf16: h, [Wq;Wk;Wv] (concat), Wo
//   2) gemm_qkv: 256^2-tile GEMM (BK=32, 4-buf, stage-ahead-3, vmcnt(8))
//   3) attn: causal flash attention, defer-max softmax, l-via-ones-MFMA
//   4) gemm_out: same GEMM core, O @ Wo^T + bo -> fp32 d_out
// ---------------------------------------------------------------------------

using bf16x8 = __attribute__((ext_vector_type(8))) __bf16;
using f32x4  = __attribute__((ext_vector_type(4))) float;
using s16x8  = __attribute__((ext_vector_type(8))) short;

#define MFMA16(a, b, c) __builtin_amdgcn_mfma_f32_16x16x32_bf16((a), (b), (c), 0, 0, 0)

__device__ __forceinline__ unsigned short f2bf(float f) {
  unsigned u = __float_as_uint(f);
  u += 0x7FFFu + ((u >> 16) & 1u);   // round-to-nearest-even (finite inputs only)
  return (unsigned short)(u >> 16);
}

__device__ __forceinline__ void gload16(const void* g, void* l) {
  __builtin_amdgcn_global_load_lds((const __attribute__((address_space(1))) void*)g,
                                   (__attribute__((address_space(3))) void*)l,
                                   16, 0, 0);
}

// ---------------------------------------------------------------------------
// fp32 -> bf16 convert, 4 elems/thread
// ---------------------------------------------------------------------------
__global__ void cvt_kernel(const float* __restrict__ in, unsigned short* __restrict__ out, int n4) {
  int i = blockIdx.x * 256 + threadIdx.x;
  if (i >= n4) return;
  float4 v = ((const float4*)in)[i];
  ushort4 o;
  o.x = f2bf(v.x); o.y = f2bf(v.y); o.z = f2bf(v.z); o.w = f2bf(v.w);
  ((ushort4*)out)[i] = o;
}

// ---------------------------------------------------------------------------
// 256x256-tile, BK=32, 8-wave (2Mx4N) GEMM core, counted-vmcnt pipeline.
// (unchanged from round 4 — verified correct, gemm_qkv left the top-5)
// ---------------------------------------------------------------------------

#define GEMM_PRE()                                                             \
  const int tid = threadIdx.x;                                                 \
  const int wave = tid >> 6, lane = tid & 63;                                  \
  const int lo = lane & 15, hi = lane >> 4;                                    \
  const int wr = wave >> 2, wc = wave & 3;                                     \
  const int r4 = lane >> 2, s4 = lane & 3;                                     \
  const int scol = ((s4 ^ (r4 & 3)) << 3);                                     \
  const unsigned short* aS[2]; const unsigned short* bS[2];                    \
  _Pragma("unroll")                                                            \
  for (int j = 0; j < 2; ++j) {                                                \
    aS[j] = A + (size_t)(m0 + (wave * 2 + j) * 16 + r4) * 2048 + scol;         \
    bS[j] = W + (size_t)(n0 + (wave * 2 + j) * 16 + r4) * 2048 + scol;         \
  }                                                                            \
  f32x4 acc[8][4] = {};

#define STAGE2(BUF, J)                                                         \
  do {                                                                         \
    gload16(aS[J], &lA[BUF][(wave * 2 + (J)) * 512]);                          \
    gload16(bS[J], &lB[BUF][(wave * 2 + (J)) * 512]);                          \
    aS[J] += 32; bS[J] += 32;                                                  \
  } while (0)

#define LDA4_(dst, MH, BUF)                                                    \
  do {                                                                         \
    _Pragma("unroll")                                                          \
    for (int im = 0; im < 4; ++im)                                             \
      dst[im] = *(const bf16x8*)&lA[BUF][(wr * 128 + (MH)*64 + im * 16 + lo) * 32 + \
                                         ((hi ^ (lo & 3)) << 3)];              \
  } while (0)

#define LDB4_(dst, BUF)                                                        \
  do {                                                                         \
    _Pragma("unroll")                                                          \
    for (int ni = 0; ni < 4; ++ni)                                             \
      dst[ni] = *(const bf16x8*)&lB[BUF][(wc * 64 + ni * 16 + lo) * 32 +       \
                                         ((hi ^ (lo & 3)) << 3)];              \
  } while (0)

#define MF16(MH, aF, bF)                                                       \
  do {                                                                         \
    __builtin_amdgcn_s_setprio(1);                                             \
    _Pragma("unroll")                                                          \
    for (int im = 0; im < 4; ++im)                                             \
      _Pragma("unroll")                                                        \
      for (int ni = 0; ni < 4; ++ni)                                           \
        acc[(MH)*4 + im][ni] = MFMA16(aF[im], bF[ni], acc[(MH)*4 + im][ni]);   \
    __builtin_amdgcn_s_setprio(0);                                             \
  } while (0)

#define BAR __builtin_amdgcn_s_barrier()
#define VMC(N) asm volatile("s_waitcnt vmcnt(" #N ")" ::: "memory")

#define TILE(RBUF, SBUF, COND, VN)                                             \
  do {                                                                         \
    bf16x8 aF[4], aG[4], bF[4];                                                \
    LDA4_(aF, 0, RBUF); LDB4_(bF, RBUF);                                       \
    if (COND) STAGE2(SBUF, 0);                                                 \
    BAR; MF16(0, aF, bF); BAR;                                                 \
    LDA4_(aG, 1, RBUF);                                                        \
    if (COND) STAGE2(SBUF, 1);                                                 \
    BAR; MF16(1, aG, bF); VMC(VN); BAR;                                        \
  } while (0)

#define GEMM_MAIN()                                                            \
  STAGE2(0, 0); STAGE2(0, 1); STAGE2(1, 0); STAGE2(1, 1);                      \
  STAGE2(2, 0); STAGE2(2, 1);                                                  \
  VMC(8); BAR;                                                                 \
  for (int u = 0; u < 15; ++u) {                                               \
    TILE(0, 3, true, 8); TILE(1, 0, true, 8);                                  \
    TILE(2, 1, true, 8); TILE(3, 2, true, 8);                                  \
  }                                                                            \
  TILE(0, 3, true, 8); TILE(1, 0, false, 4);                                   \
  TILE(2, 1, false, 0); TILE(3, 2, false, 0);

// ---------------------------------------------------------------------------
// QKV GEMM: M=8192 (B*S), N=6144 (Wq;Wk;Wv), K=2048. Output scattered into
// Q/K/V [b,nh,S,hd] bf16 with bias.
// ---------------------------------------------------------------------------
__global__ __launch_bounds__(512, 2)
void gemm_qkv(const unsigned short* __restrict__ A,
              const unsigned short* __restrict__ W,
              const float* __restrict__ bq, const float* __restrict__ bk,
              const float* __restrict__ bv,
              unsigned short* __restrict__ Q, unsigned short* __restrict__ Kq,
              unsigned short* __restrict__ V) {
  __shared__ unsigned short lA[4][256 * 32];
  __shared__ unsigned short lB[4][256 * 32];
  const int bid = blockIdx.x;
  const int sid = (bid & 7) * 96 + (bid >> 3);
  const int bm = sid / 24, bn = sid % 24;
  const int m0 = bm * 256, n0 = bn * 256;
  GEMM_PRE();
  GEMM_MAIN();

  const int which = n0 >> 11;
  const float* bias = (which == 0) ? bq : (which == 1) ? bk : bv;
  unsigned short* dst = (which == 0) ? Q : (which == 1) ? Kq : V;
#pragma unroll
  for (int mi = 0; mi < 8; mi++)
#pragma unroll
    for (int ni = 0; ni < 4; ni++) {
      int n_g = n0 + wc * 64 + ni * 16 + lo;
      int n2 = n_g & 2047;
      int head = n2 >> 7, d = n2 & 127;
      float bb = bias[n2];
#pragma unroll
      for (int i = 0; i < 4; i++) {
        int m = m0 + wr * 128 + mi * 16 + hi * 4 + i;
        int b = m >> 11, s = m & 2047;
        dst[(((size_t)b * 16 + head) * 2048 + s) * 128 + d] = f2bf(acc[mi][ni][i] + bb);
      }
    }
}

// ---------------------------------------------------------------------------
// Output GEMM: M=8192, N=2048, K=2048, fp32 out + bias.
// ---------------------------------------------------------------------------
__global__ __launch_bounds__(512, 2)
void gemm_out(const unsigned short* __restrict__ A,
              const unsigned short* __restrict__ W,
              const float* __restrict__ bo, float* __restrict__ out) {
  __shared__ unsigned short lA[4][256 * 32];
  __shared__ unsigned short lB[4][256 * 32];
  const int bid = blockIdx.x;
  const int sid = (bid & 7) * 32 + (bid >> 3);
  const int bm = sid >> 3, bn = sid & 7;
  const int m0 = bm * 256, n0 = bn * 256;
  GEMM_PRE();
  GEMM_MAIN();

#pragma unroll
  for (int mi = 0; mi < 8; mi++)
#pragma unroll
    for (int ni = 0; ni < 4; ni++) {
      int n_g = n0 + wc * 64 + ni * 16 + lo;
      float bb = bo[n_g];
#pragma unroll
      for (int i = 0; i < 4; i++) {
        int m = m0 + wr * 128 + mi * 16 + hi * 4 + i;
        out[(size_t)m * 2048 + n_g] = acc[mi][ni][i] + bb;
      }
    }
}

// ---------------------------------------------------------------------------
// Causal flash attention. Grid: 64 (bh) x 16 (q-tiles of 128). 4 waves/block,
// wave w owns rows q0 = qt*128 + w*32 .. +31 (2 m-frags of 16).
// Softmax in log2 domain with defer-max (T13): fast path (no shuffles, no
// rescale) when all rows' tile-max <= running max + 11.54 (= e^8 bound);
// slow path (first tile / rare growth) does the shfl row-max + acc rescale.
// Denominator l computed by MFMA against a ones-column block of V
// (acc[*][8]) so it rescales with acc for free — no sum shuffles.
// K-tile swizzled via pre-swizzled global_load_lds source; V^T in LDS with
// pad 42 (odd dword stride -> conflict-free staging writes).
// ---------------------------------------------------------------------------
__global__ __launch_bounds__(256, 2)
void attn_kernel(const unsigned short* __restrict__ Qb,
                 const unsigned short* __restrict__ Kb,
                 const unsigned short* __restrict__ Vb,
                 unsigned short* __restrict__ Ob) {
  __shared__ unsigned short lK[32 * 128];       // swizzled row-major [32][128]
  __shared__ unsigned short lVt[144 * 42];      // V^T [d 0..127 | ones 128..143][32 k], pad 42
  __shared__ unsigned short lP[4][32 * 40];     // per-wave P tile [32 q][32 k], pad 40

  const int tid = threadIdx.x;
  const int wave = tid >> 6, lane = tid & 63;
  const int lo = lane & 15, hi = lane >> 4;
  const int bh = blockIdx.x & 63;
  const int qt = 15 - (blockIdx.x >> 6);        // heavy tiles dispatched first
  const int q0 = qt * 128 + wave * 32;
  const size_t base = (size_t)bh * 2048 * 128;
  // scores kept in log2 domain: s2 = s_raw * (1/sqrt(128) * log2(e))
  const float SCL = 0.08838834764831845f * 1.4426950408889634f;
  const float THR = 11.5416f;                   // 8 * log2(e)

  // ones rows (d=128..143) written once; first use is after 2 barriers
#pragma unroll
  for (int x = tid; x < 512; x += 256)
    lVt[(128 + (x >> 5)) * 42 + (x & 31)] = 0x3F80;  // bf16 1.0

  // Q fragments in registers: rows q0+mi*16+lo, d = dk*32 + hi*8 ..+7
  bf16x8 aq[2][4];
#pragma unroll
  for (int mi = 0; mi < 2; mi++)
#pragma unroll
    for (int dk = 0; dk < 4; dk++)
      aq[mi][dk] = *(const bf16x8*)&Qb[base + (size_t)(q0 + mi * 16 + lo) * 128 + dk * 32 + hi * 8];

  f32x4 acc[2][9] = {};                         // [.][8] = l (ones column)
  float mrun[2][4];
#pragma unroll
  for (int a = 0; a < 2; a++)
#pragma unroll
    for (int b = 0; b < 4; b++) mrun[a][b] = -INFINITY;

  const int ktn = qt * 4 + 4;                   // tiles covering k <= q0_block+127
  const int qmax_w = q0 + 31;

  for (int kt = 0; kt < ktn; kt++) {
    __syncthreads();
    // ---- stage K tile (swizzled source -> linear LDS dest) ----
#pragma unroll
    for (int j = 0; j < 2; j++) {
      int c = wave * 2 + j;
      int row = c * 4 + hi;                                  // 0..31
      int srccol = (lo * 16) ^ ((row & 7) << 4);             // byte offset in 256B row
      const unsigned short* g = Kb + base + (size_t)(kt * 32 + row) * 128 + (srccol >> 1);
      gload16(g, &lK[c * 512]);
    }
    // ---- stage V transposed: thread -> rows {2rr,2rr+1}, cols c0..c0+7 ----
    {
      int rr = tid & 15;
      int c0 = (tid >> 4) * 8;
      const unsigned short* vp = Vb + base + (size_t)(kt * 32 + 2 * rr) * 128 + c0;
      s16x8 va = *(const s16x8*)vp;
      s16x8 vb2 = *(const s16x8*)(vp + 128);
#pragma unroll
      for (int j = 0; j < 8; j++)
        *(ushort2*)&lVt[(c0 + j) * 42 + 2 * rr] =
            make_ushort2((unsigned short)va[j], (unsigned short)vb2[j]);
    }
    __syncthreads();

    if (kt * 32 <= qmax_w) {                    // wave-uniform: tile not fully masked
      // ---- scores: S[32q][32k] ----
      f32x4 sc[2][2] = {};
#pragma unroll
      for (int ni = 0; ni < 2; ni++)
#pragma unroll
        for (int dk = 0; dk < 4; dk++) {
          int row = ni * 16 + lo;
          int col = (dk * 32 + hi * 8) ^ ((row & 7) << 3);   // element-index swizzle
          bf16x8 bk_ = *(const bf16x8*)&lK[row * 128 + col];
          sc[0][ni] = MFMA16(aq[0][dk], bk_, sc[0][ni]);
          sc[1][ni] = MFMA16(aq[1][dk], bk_, sc[1][ni]);
        }

      // ---- scale + causal mask (log2 domain), defer-max condition ----
      float s0_[2][4], s1_[2][4];
      bool cond = true;
#pragma unroll
      for (int mi = 0; mi < 2; mi++)
#pragma unroll
        for (int i = 0; i < 4; i++) {
          int qrow = q0 + mi * 16 + hi * 4 + i;
          int kc = kt * 32 + lo;
          float s0 = sc[mi][0][i] * SCL;
          float s1 = sc[mi][1][i] * SCL;
          if (kc > qrow) s0 = -INFINITY;
          if (kc + 16 > qrow) s1 = -INFINITY;
          s0_[mi][i] = s0; s1_[mi][i] = s1;
          cond = cond && (fmaxf(s0, s1) <= mrun[mi][i] + THR);
        }

      if (!__all((int)cond)) {
        // ---- slow path: per-row shfl max, rescale acc (incl. l column) ----
#pragma unroll
        for (int mi = 0; mi < 2; mi++)
#pragma unroll
          for (int i = 0; i < 4; i++) {
            float mt = fmaxf(s0_[mi][i], s1_[mi][i]);
            mt = fmaxf(mt, __shfl_xor(mt, 1));
            mt = fmaxf(mt, __shfl_xor(mt, 2));
            mt = fmaxf(mt, __shfl_xor(mt, 4));
            mt = fmaxf(mt, __shfl_xor(mt, 8));
            float mo = mrun[mi][i];
            float mn = fmaxf(mo, mt);
            float alpha = exp2f(mo - mn);       // exp2(-inf)=0 handles first tile
            mrun[mi][i] = mn;
#pragma unroll
            for (int ni = 0; ni < 9; ni++) acc[mi][ni][i] *= alpha;
          }
      }

      // ---- P = exp2(s - m), store to per-wave LDS tile ----
      unsigned short* lPw = &lP[wave][0];
#pragma unroll
      for (int mi = 0; mi < 2; mi++)
#pragma unroll
        for (int i = 0; i < 4; i++) {
          float m = mrun[mi][i];
          float p0 = exp2f(s0_[mi][i] - m);
          float p1 = exp2f(s1_[mi][i] - m);
          int prow = mi * 16 + hi * 4 + i;
          lPw[prow * 40 + lo] = f2bf(p0);
          lPw[prow * 40 + 16 + lo] = f2bf(p1);
        }

      // ---- PV: O += P * V' (ni=8 is the ones block -> l) ----
      bf16x8 ap0 = *(const bf16x8*)&lPw[(lo) * 40 + hi * 8];
      bf16x8 ap1 = *(const bf16x8*)&lPw[(16 + lo) * 40 + hi * 8];
#pragma unroll
      for (int ni = 0; ni < 9; ni++) {
        bf16x8 bv_ = *(const bf16x8*)&lVt[(ni * 16 + lo) * 42 + hi * 8];
        acc[0][ni] = MFMA16(ap0, bv_, acc[0][ni]);
        acc[1][ni] = MFMA16(ap1, bv_, acc[1][ni]);
      }
    }
  }

  // ---- epilogue: O[b, s, h*128+d] = acc / l, l = acc[mi][8][i] ----
  const int b = bh >> 4, hh = bh & 15;
#pragma unroll
  for (int mi = 0; mi < 2; mi++)
#pragma unroll
    for (int i = 0; i < 4; i++) {
      float inv = 1.0f / acc[mi][8][i];
      int s = q0 + mi * 16 + hi * 4 + i;
      size_t rowbase = ((size_t)b * 2048 + s) * 2048 + hh * 128 + lo;
#pragma unroll
      for (int ni = 0; ni < 8; ni++)
        Ob[rowbase + ni * 16] = f2bf(acc[mi][ni][i] * inv);
    }
}

// ---------------------------------------------------------------------------
extern "C" void kernel_launch(void* const* d_in, const int* in_sizes, int n_in,
                              void* d_out, int out_size, void* d_ws, size_t ws_size,
                              hipStream_t stream) {
  const float* h  = (const float*)d_in[0];
  const float* Wq = (const float*)d_in[1];
  const float* bq = (const float*)d_in[2];
  const float* Wk = (const float*)d_in[3];
  const float* bk = (const float*)d_in[4];
  const float* Wv = (const float*)d_in[5];
  const float* bv = (const float*)d_in[6];
  const float* Wo = (const float*)d_in[7];
  const float* bo = (const float*)d_in[8];
  float* out = (float*)d_out;

  char* ws = (char*)d_ws;
  unsigned short* h_bf  = (unsigned short*)(ws + 0);            // 32 MiB
  unsigned short* Qb    = (unsigned short*)(ws + 33554432);     // 32 MiB
  unsigned short* Kb    = (unsigned short*)(ws + 67108864);     // 32 MiB
  unsigned short* Vb    = (unsigned short*)(ws + 100663296);    // 32 MiB
  unsigned short* Wqkv  = (unsigned short*)(ws + 134217728);    // 24 MiB
  unsigned short* Wo_bf = (unsigned short*)(ws + 159383552);    // 8 MiB
  unsigned short* Ob    = h_bf;                                 // reuse after QKV GEMM

  // fp32 -> bf16 conversions
  cvt_kernel<<<16384, 256, 0, stream>>>(h, h_bf, 4194304);
  cvt_kernel<<<4096, 256, 0, stream>>>(Wq, Wqkv, 1048576);
  cvt_kernel<<<4096, 256, 0, stream>>>(Wk, Wqkv + 4194304, 1048576);
  cvt_kernel<<<4096, 256, 0, stream>>>(Wv, Wqkv + 8388608, 1048576);
  cvt_kernel<<<4096, 256, 0, stream>>>(Wo, Wo_bf, 1048576);

  // QKV projection (M=8192, N=6144, K=2048), 32x24 blocks of 256x256
  gemm_qkv<<<dim3(768), dim3(512), 0, stream>>>(h_bf, Wqkv, bq, bk, bv, Qb, Kb, Vb);

  // causal attention (64 bh x 16 q-tiles)
  attn_kernel<<<dim3(1024), dim3(256), 0, stream>>>(Qb, Kb, Vb, Ob);

  // output projection (M=8192, N=2048, K=2048), 32x8 blocks, fp32 out
  gemm_out<<<dim3(256), dim3(512), 0, stream>>>(Ob, Wo_bf, bo, out);
}

// Round 6
// 456.790 us; speedup vs baseline: 1.2222x; 1.0245x over previous
//
#include <hip/hip_runtime.h>
#include <hip/hip_bf16.h>
#include <math.h>

// ---------------------------------------------------------------------------
// GPT2 attention block: out = Attn(h) for B=4, S=2048, H=2048, nh=16, hd=128
// Pipeline (all bf16 MFMA, fp32 accumulate):
//   1) cvt fp32->bf16: h, [Wq;Wk;Wv] (concat), Wo
//   2) gemm_qkv: 256^2-tile GEMM (BK=32, 4-buf, stage-ahead-3, vmcnt(8))
//   3) attn: causal flash attention, defer-max softmax, l-via-ones-MFMA
//   4) gemm_out: same GEMM core, O @ Wo^T + bo -> fp32 d_out
// ---------------------------------------------------------------------------

using bf16x8 = __attribute__((ext_vector_type(8))) __bf16;
using f32x4  = __attribute__((ext_vector_type(4))) float;
using s16x8  = __attribute__((ext_vector_type(8))) short;

#define MFMA16(a, b, c) __builtin_amdgcn_mfma_f32_16x16x32_bf16((a), (b), (c), 0, 0, 0)

__device__ __forceinline__ unsigned short f2bf(float f) {
  unsigned u = __float_as_uint(f);
  u += 0x7FFFu + ((u >> 16) & 1u);   // round-to-nearest-even (finite inputs only)
  return (unsigned short)(u >> 16);
}

__device__ __forceinline__ void gload16(const void* g, void* l) {
  __builtin_amdgcn_global_load_lds((const __attribute__((address_space(1))) void*)g,
                                   (__attribute__((address_space(3))) void*)l,
                                   16, 0, 0);
}

// ---------------------------------------------------------------------------
// fp32 -> bf16 convert, 4 elems/thread
// ---------------------------------------------------------------------------
__global__ void cvt_kernel(const float* __restrict__ in, unsigned short* __restrict__ out, int n4) {
  int i = blockIdx.x * 256 + threadIdx.x;
  if (i >= n4) return;
  float4 v = ((const float4*)in)[i];
  ushort4 o;
  o.x = f2bf(v.x); o.y = f2bf(v.y); o.z = f2bf(v.z); o.w = f2bf(v.w);
  ((ushort4*)out)[i] = o;
}

// ---------------------------------------------------------------------------
// 256x256-tile, BK=32, 8-wave (2Mx4N) GEMM core, counted-vmcnt pipeline.
// Swizzle g(r) = (r>>1)&3 (NOT r&3): ds_read_b128 is serviced in 8-lane
// groups; window index = 4*(row&1) + (slot). With g=(r>>1)&3 the 8 windows
// per group are a bijection onto 0..7 -> conflict-free (round-2 property);
// with g=r&3, lanes lo and lo+4 collide (2-way, 1.9e7 conflicts measured).
// Applied both-sides: pre-swizzled global source + swizzled ds_read.
// ---------------------------------------------------------------------------

#define GEMM_PRE()                                                             \
  const int tid = threadIdx.x;                                                 \
  const int wave = tid >> 6, lane = tid & 63;                                  \
  const int lo = lane & 15, hi = lane >> 4;                                    \
  const int wr = wave >> 2, wc = wave & 3;                                     \
  const int r4 = lane >> 2, s4 = lane & 3;                                     \
  const int scol = ((s4 ^ ((r4 >> 1) & 3)) << 3);                              \
  const unsigned short* aS[2]; const unsigned short* bS[2];                    \
  _Pragma("unroll")                                                            \
  for (int j = 0; j < 2; ++j) {                                                \
    aS[j] = A + (size_t)(m0 + (wave * 2 + j) * 16 + r4) * 2048 + scol;         \
    bS[j] = W + (size_t)(n0 + (wave * 2 + j) * 16 + r4) * 2048 + scol;         \
  }                                                                            \
  f32x4 acc[8][4] = {};

#define STAGE2(BUF, J)                                                         \
  do {                                                                         \
    gload16(aS[J], &lA[BUF][(wave * 2 + (J)) * 512]);                          \
    gload16(bS[J], &lB[BUF][(wave * 2 + (J)) * 512]);                          \
    aS[J] += 32; bS[J] += 32;                                                  \
  } while (0)

#define LDA4_(dst, MH, BUF)                                                    \
  do {                                                                         \
    _Pragma("unroll")                                                          \
    for (int im = 0; im < 4; ++im)                                             \
      dst[im] = *(const bf16x8*)&lA[BUF][(wr * 128 + (MH)*64 + im * 16 + lo) * 32 + \
                                         ((hi ^ ((lo >> 1) & 3)) << 3)];       \
  } while (0)

#define LDB4_(dst, BUF)                                                        \
  do {                                                                         \
    _Pragma("unroll")                                                          \
    for (int ni = 0; ni < 4; ++ni)                                             \
      dst[ni] = *(const bf16x8*)&lB[BUF][(wc * 64 + ni * 16 + lo) * 32 +       \
                                         ((hi ^ ((lo >> 1) & 3)) << 3)];       \
  } while (0)

#define MF16(MH, aF, bF)                                                       \
  do {                                                                         \
    __builtin_amdgcn_s_setprio(1);                                             \
    _Pragma("unroll")                                                          \
    for (int im = 0; im < 4; ++im)                                             \
      _Pragma("unroll")                                                        \
      for (int ni = 0; ni < 4; ++ni)                                           \
        acc[(MH)*4 + im][ni] = MFMA16(aF[im], bF[ni], acc[(MH)*4 + im][ni]);   \
    __builtin_amdgcn_s_setprio(0);                                             \
  } while (0)

#define BAR __builtin_amdgcn_s_barrier()
#define VMC(N) asm volatile("s_waitcnt vmcnt(" #N ")" ::: "memory")

#define TILE(RBUF, SBUF, COND, VN)                                             \
  do {                                                                         \
    bf16x8 aF[4], aG[4], bF[4];                                                \
    LDA4_(aF, 0, RBUF); LDB4_(bF, RBUF);                                       \
    if (COND) STAGE2(SBUF, 0);                                                 \
    BAR; MF16(0, aF, bF); BAR;                                                 \
    LDA4_(aG, 1, RBUF);                                                        \
    if (COND) STAGE2(SBUF, 1);                                                 \
    BAR; MF16(1, aG, bF); VMC(VN); BAR;                                        \
  } while (0)

#define GEMM_MAIN()                                                            \
  STAGE2(0, 0); STAGE2(0, 1); STAGE2(1, 0); STAGE2(1, 1);                      \
  STAGE2(2, 0); STAGE2(2, 1);                                                  \
  VMC(8); BAR;                                                                 \
  for (int u = 0; u < 15; ++u) {                                               \
    TILE(0, 3, true, 8); TILE(1, 0, true, 8);                                  \
    TILE(2, 1, true, 8); TILE(3, 2, true, 8);                                  \
  }                                                                            \
  TILE(0, 3, true, 8); TILE(1, 0, false, 4);                                   \
  TILE(2, 1, false, 0); TILE(3, 2, false, 0);

// ---------------------------------------------------------------------------
// QKV GEMM: M=8192 (B*S), N=6144 (Wq;Wk;Wv), K=2048. Output scattered into
// Q/K/V [b,nh,S,hd] bf16 with bias.
// ---------------------------------------------------------------------------
__global__ __launch_bounds__(512, 2)
void gemm_qkv(const unsigned short* __restrict__ A,
              const unsigned short* __restrict__ W,
              const float* __restrict__ bq, const float* __restrict__ bk,
              const float* __restrict__ bv,
              unsigned short* __restrict__ Q, unsigned short* __restrict__ Kq,
              unsigned short* __restrict__ V) {
  __shared__ unsigned short lA[4][256 * 32];
  __shared__ unsigned short lB[4][256 * 32];
  const int bid = blockIdx.x;
  const int sid = (bid & 7) * 96 + (bid >> 3);
  const int bm = sid / 24, bn = sid % 24;
  const int m0 = bm * 256, n0 = bn * 256;
  GEMM_PRE();
  GEMM_MAIN();

  const int which = n0 >> 11;
  const float* bias = (which == 0) ? bq : (which == 1) ? bk : bv;
  unsigned short* dst = (which == 0) ? Q : (which == 1) ? Kq : V;
#pragma unroll
  for (int mi = 0; mi < 8; mi++)
#pragma unroll
    for (int ni = 0; ni < 4; ni++) {
      int n_g = n0 + wc * 64 + ni * 16 + lo;
      int n2 = n_g & 2047;
      int head = n2 >> 7, d = n2 & 127;
      float bb = bias[n2];
#pragma unroll
      for (int i = 0; i < 4; i++) {
        int m = m0 + wr * 128 + mi * 16 + hi * 4 + i;
        int b = m >> 11, s = m & 2047;
        dst[(((size_t)b * 16 + head) * 2048 + s) * 128 + d] = f2bf(acc[mi][ni][i] + bb);
      }
    }
}

// ---------------------------------------------------------------------------
// Output GEMM: M=8192, N=2048, K=2048, fp32 out + bias.
// ---------------------------------------------------------------------------
__global__ __launch_bounds__(512, 2)
void gemm_out(const unsigned short* __restrict__ A,
              const unsigned short* __restrict__ W,
              const float* __restrict__ bo, float* __restrict__ out) {
  __shared__ unsigned short lA[4][256 * 32];
  __shared__ unsigned short lB[4][256 * 32];
  const int bid = blockIdx.x;
  const int sid = (bid & 7) * 32 + (bid >> 3);
  const int bm = sid >> 3, bn = sid & 7;
  const int m0 = bm * 256, n0 = bn * 256;
  GEMM_PRE();
  GEMM_MAIN();

#pragma unroll
  for (int mi = 0; mi < 8; mi++)
#pragma unroll
    for (int ni = 0; ni < 4; ni++) {
      int n_g = n0 + wc * 64 + ni * 16 + lo;
      float bb = bo[n_g];
#pragma unroll
      for (int i = 0; i < 4; i++) {
        int m = m0 + wr * 128 + mi * 16 + hi * 4 + i;
        out[(size_t)m * 2048 + n_g] = acc[mi][ni][i] + bb;
      }
    }
}

// ---------------------------------------------------------------------------
// Causal flash attention. Grid: 64 (bh) x 16 (q-tiles of 128). 4 waves/block,
// wave w owns rows q0 = qt*128 + w*32 .. +31 (2 m-frags of 16).
// Softmax in log2 domain with defer-max (T13); denominator l via ones-column
// MFMA (acc[*][8]). (unchanged from round 5)
// ---------------------------------------------------------------------------
__global__ __launch_bounds__(256, 2)
void attn_kernel(const unsigned short* __restrict__ Qb,
                 const unsigned short* __restrict__ Kb,
                 const unsigned short* __restrict__ Vb,
                 unsigned short* __restrict__ Ob) {
  __shared__ unsigned short lK[32 * 128];       // swizzled row-major [32][128]
  __shared__ unsigned short lVt[144 * 42];      // V^T [d 0..127 | ones 128..143][32 k], pad 42
  __shared__ unsigned short lP[4][32 * 40];     // per-wave P tile [32 q][32 k], pad 40

  const int tid = threadIdx.x;
  const int wave = tid >> 6, lane = tid & 63;
  const int lo = lane & 15, hi = lane >> 4;
  const int bh = blockIdx.x & 63;
  const int qt = 15 - (blockIdx.x >> 6);        // heavy tiles dispatched first
  const int q0 = qt * 128 + wave * 32;
  const size_t base = (size_t)bh * 2048 * 128;
  // scores kept in log2 domain: s2 = s_raw * (1/sqrt(128) * log2(e))
  const float SCL = 0.08838834764831845f * 1.4426950408889634f;
  const float THR = 11.5416f;                   // 8 * log2(e)

  // ones rows (d=128..143) written once; first use is after 2 barriers
#pragma unroll
  for (int x = tid; x < 512; x += 256)
    lVt[(128 + (x >> 5)) * 42 + (x & 31)] = 0x3F80;  // bf16 1.0

  // Q fragments in registers: rows q0+mi*16+lo, d = dk*32 + hi*8 ..+7
  bf16x8 aq[2][4];
#pragma unroll
  for (int mi = 0; mi < 2; mi++)
#pragma unroll
    for (int dk = 0; dk < 4; dk++)
      aq[mi][dk] = *(const bf16x8*)&Qb[base + (size_t)(q0 + mi * 16 + lo) * 128 + dk * 32 + hi * 8];

  f32x4 acc[2][9] = {};                         // [.][8] = l (ones column)
  float mrun[2][4];
#pragma unroll
  for (int a = 0; a < 2; a++)
#pragma unroll
    for (int b = 0; b < 4; b++) mrun[a][b] = -INFINITY;

  const int ktn = qt * 4 + 4;                   // tiles covering k <= q0_block+127
  const int qmax_w = q0 + 31;

  for (int kt = 0; kt < ktn; kt++) {
    __syncthreads();
    // ---- stage K tile (swizzled source -> linear LDS dest) ----
#pragma unroll
    for (int j = 0; j < 2; j++) {
      int c = wave * 2 + j;
      int row = c * 4 + hi;                                  // 0..31
      int srccol = (lo * 16) ^ ((row & 7) << 4);             // byte offset in 256B row
      const unsigned short* g = Kb + base + (size_t)(kt * 32 + row) * 128 + (srccol >> 1);
      gload16(g, &lK[c * 512]);
    }
    // ---- stage V transposed: thread -> rows {2rr,2rr+1}, cols c0..c0+7 ----
    {
      int rr = tid & 15;
      int c0 = (tid >> 4) * 8;
      const unsigned short* vp = Vb + base + (size_t)(kt * 32 + 2 * rr) * 128 + c0;
      s16x8 va = *(const s16x8*)vp;
      s16x8 vb2 = *(const s16x8*)(vp + 128);
#pragma unroll
      for (int j = 0; j < 8; j++)
        *(ushort2*)&lVt[(c0 + j) * 42 + 2 * rr] =
            make_ushort2((unsigned short)va[j], (unsigned short)vb2[j]);
    }
    __syncthreads();

    if (kt * 32 <= qmax_w) {                    // wave-uniform: tile not fully masked
      // ---- scores: S[32q][32k] ----
      f32x4 sc[2][2] = {};
#pragma unroll
      for (int ni = 0; ni < 2; ni++)
#pragma unroll
        for (int dk = 0; dk < 4; dk++) {
          int row = ni * 16 + lo;
          int col = (dk * 32 + hi * 8) ^ ((row & 7) << 3);   // element-index swizzle
          bf16x8 bk_ = *(const bf16x8*)&lK[row * 128 + col];
          sc[0][ni] = MFMA16(aq[0][dk], bk_, sc[0][ni]);
          sc[1][ni] = MFMA16(aq[1][dk], bk_, sc[1][ni]);
        }

      // ---- scale + causal mask (log2 domain), defer-max condition ----
      float s0_[2][4], s1_[2][4];
      bool cond = true;
#pragma unroll
      for (int mi = 0; mi < 2; mi++)
#pragma unroll
        for (int i = 0; i < 4; i++) {
          int qrow = q0 + mi * 16 + hi * 4 + i;
          int kc = kt * 32 + lo;
          float s0 = sc[mi][0][i] * SCL;
          float s1 = sc[mi][1][i] * SCL;
          if (kc > qrow) s0 = -INFINITY;
          if (kc + 16 > qrow) s1 = -INFINITY;
          s0_[mi][i] = s0; s1_[mi][i] = s1;
          cond = cond && (fmaxf(s0, s1) <= mrun[mi][i] + THR);
        }

      if (!__all((int)cond)) {
        // ---- slow path: per-row shfl max, rescale acc (incl. l column) ----
#pragma unroll
        for (int mi = 0; mi < 2; mi++)
#pragma unroll
          for (int i = 0; i < 4; i++) {
            float mt = fmaxf(s0_[mi][i], s1_[mi][i]);
            mt = fmaxf(mt, __shfl_xor(mt, 1));
            mt = fmaxf(mt, __shfl_xor(mt, 2));
            mt = fmaxf(mt, __shfl_xor(mt, 4));
            mt = fmaxf(mt, __shfl_xor(mt, 8));
            float mo = mrun[mi][i];
            float mn = fmaxf(mo, mt);
            float alpha = exp2f(mo - mn);       // exp2(-inf)=0 handles first tile
            mrun[mi][i] = mn;
#pragma unroll
            for (int ni = 0; ni < 9; ni++) acc[mi][ni][i] *= alpha;
          }
      }

      // ---- P = exp2(s - m), store to per-wave LDS tile ----
      unsigned short* lPw = &lP[wave][0];
#pragma unroll
      for (int mi = 0; mi < 2; mi++)
#pragma unroll
        for (int i = 0; i < 4; i++) {
          float m = mrun[mi][i];
          float p0 = exp2f(s0_[mi][i] - m);
          float p1 = exp2f(s1_[mi][i] - m);
          int prow = mi * 16 + hi * 4 + i;
          lPw[prow * 40 + lo] = f2bf(p0);
          lPw[prow * 40 + 16 + lo] = f2bf(p1);
        }

      // ---- PV: O += P * V' (ni=8 is the ones block -> l) ----
      bf16x8 ap0 = *(const bf16x8*)&lPw[(lo) * 40 + hi * 8];
      bf16x8 ap1 = *(const bf16x8*)&lPw[(16 + lo) * 40 + hi * 8];
#pragma unroll
      for (int ni = 0; ni < 9; ni++) {
        bf16x8 bv_ = *(const bf16x8*)&lVt[(ni * 16 + lo) * 42 + hi * 8];
        acc[0][ni] = MFMA16(ap0, bv_, acc[0][ni]);
        acc[1][ni] = MFMA16(ap1, bv_, acc[1][ni]);
      }
    }
  }

  // ---- epilogue: O[b, s, h*128+d] = acc / l, l = acc[mi][8][i] ----
  const int b = bh >> 4, hh = bh & 15;
#pragma unroll
  for (int mi = 0; mi < 2; mi++)
#pragma unroll
    for (int i = 0; i < 4; i++) {
      float inv = 1.0f / acc[mi][8][i];
      int s = q0 + mi * 16 + hi * 4 + i;
      size_t rowbase = ((size_t)b * 2048 + s) * 2048 + hh * 128 + lo;
#pragma unroll
      for (int ni = 0; ni < 8; ni++)
        Ob[rowbase + ni * 16] = f2bf(acc[mi][ni][i] * inv);
    }
}

// ---------------------------------------------------------------------------
extern "C" void kernel_launch(void* const* d_in, const int* in_sizes, int n_in,
                              void* d_out, int out_size, void* d_ws, size_t ws_size,
                              hipStream_t stream) {
  const float* h  = (const float*)d_in[0];
  const float* Wq = (const float*)d_in[1];
  const float* bq = (const float*)d_in[2];
  const float* Wk = (const float*)d_in[3];
  const float* bk = (const float*)d_in[4];
  const float* Wv = (const float*)d_in[5];
  const float* bv = (const float*)d_in[6];
  const float* Wo = (const float*)d_in[7];
  const float* bo = (const float*)d_in[8];
  float* out = (float*)d_out;

  char* ws = (char*)d_ws;
  unsigned short* h_bf  = (unsigned short*)(ws + 0);            // 32 MiB
  unsigned short* Qb    = (unsigned short*)(ws + 33554432);     // 32 MiB
  unsigned short* Kb    = (unsigned short*)(ws + 67108864);     // 32 MiB
  unsigned short* Vb    = (unsigned short*)(ws + 100663296);    // 32 MiB
  unsigned short* Wqkv  = (unsigned short*)(ws + 134217728);    // 24 MiB
  unsigned short* Wo_bf = (unsigned short*)(ws + 159383552);    // 8 MiB
  unsigned short* Ob    = h_bf;                                 // reuse after QKV GEMM

  // fp32 -> bf16 conversions
  cvt_kernel<<<16384, 256, 0, stream>>>(h, h_bf, 4194304);
  cvt_kernel<<<4096, 256, 0, stream>>>(Wq, Wqkv, 1048576);
  cvt_kernel<<<4096, 256, 0, stream>>>(Wk, Wqkv + 4194304, 1048576);
  cvt_kernel<<<4096, 256, 0, stream>>>(Wv, Wqkv + 8388608, 1048576);
  cvt_kernel<<<4096, 256, 0, stream>>>(Wo, Wo_bf, 1048576);

  // QKV projection (M=8192, N=6144, K=2048), 32x24 blocks of 256x256
  gemm_qkv<<<dim3(768), dim3(512), 0, stream>>>(h_bf, Wqkv, bq, bk, bv, Qb, Kb, Vb);

  // causal attention (64 bh x 16 q-tiles)
  attn_kernel<<<dim3(1024), dim3(256), 0, stream>>>(Qb, Kb, Vb, Ob);

  // output projection (M=8192, N=2048, K=2048), 32x8 blocks, fp32 out
  gemm_out<<<dim3(256), dim3(512), 0, stream>>>(Ob, Wo_bf, bo, out);
}

// Round 7
// 455.128 us; speedup vs baseline: 1.2266x; 1.0037x over previous
//
#include <hip/hip_runtime.h>
#include <hip/hip_bf16.h>
#include <math.h>

// ---------------------------------------------------------------------------
// GPT2 attention block: out = Attn(h) for B=4, S=2048, H=2048, nh=16, hd=128
// Pipeline (all bf16 MFMA, fp32 accumulate):
//   1) cvt fp32->bf16: h, [Wq;Wk;Wv] (concat), Wo
//   2) gemm_qkv: 256^2-tile GEMM (BK=32, 4-buf, stage-ahead-3, vmcnt(8),
//      single barrier-window per K-tile with mid-cluster ds_read interleave)
//   3) attn: causal flash attention, KVBLK=64, defer-max, l-via-ones-MFMA
//   4) gemm_out: same GEMM core, O @ Wo^T + bo -> fp32 d_out
// ---------------------------------------------------------------------------

using bf16x8 = __attribute__((ext_vector_type(8))) __bf16;
using f32x4  = __attribute__((ext_vector_type(4))) float;
using s16x8  = __attribute__((ext_vector_type(8))) short;

#define MFMA16(a, b, c) __builtin_amdgcn_mfma_f32_16x16x32_bf16((a), (b), (c), 0, 0, 0)

__device__ __forceinline__ unsigned short f2bf(float f) {
  unsigned u = __float_as_uint(f);
  u += 0x7FFFu + ((u >> 16) & 1u);   // round-to-nearest-even (finite inputs only)
  return (unsigned short)(u >> 16);
}

__device__ __forceinline__ void gload16(const void* g, void* l) {
  __builtin_amdgcn_global_load_lds((const __attribute__((address_space(1))) void*)g,
                                   (__attribute__((address_space(3))) void*)l,
                                   16, 0, 0);
}

// ---------------------------------------------------------------------------
// fp32 -> bf16 convert, 4 elems/thread
// ---------------------------------------------------------------------------
__global__ void cvt_kernel(const float* __restrict__ in, unsigned short* __restrict__ out, int n4) {
  int i = blockIdx.x * 256 + threadIdx.x;
  if (i >= n4) return;
  float4 v = ((const float4*)in)[i];
  ushort4 o;
  o.x = f2bf(v.x); o.y = f2bf(v.y); o.z = f2bf(v.z); o.w = f2bf(v.w);
  ((ushort4*)out)[i] = o;
}

// ---------------------------------------------------------------------------
// 256x256-tile, BK=32, 8-wave (2Mx4N) GEMM core, counted-vmcnt pipeline.
// One barrier window per K-tile: {8 ds_read + 4 gload; BAR; 16 MFMA;
// 4 ds_read (mh1, overlaps mh0 MFMAs); 16 MFMA; VMC(N); BAR}.
// Buffer lifecycle: tile t reads buf t%4, stages t+3 into (t+3)%4 (= buf of
// t-1, consumed before t-1's trailing barrier). Steady wait vmcnt(8) = only
// tile t+1's 4 loads must land; tail 8/4/0/0.
// Swizzle g(r)=(r>>1)&3 on 16B slots, both-sides (verified 0 conflicts).
// ---------------------------------------------------------------------------

#define GEMM_PRE()                                                             \
  const int tid = threadIdx.x;                                                 \
  const int wave = tid >> 6, lane = tid & 63;                                  \
  const int lo = lane & 15, hi = lane >> 4;                                    \
  const int wr = wave >> 2, wc = wave & 3;                                     \
  const int r4 = lane >> 2, s4 = lane & 3;                                     \
  const int scol = ((s4 ^ ((r4 >> 1) & 3)) << 3);                              \
  const unsigned short* aS[2]; const unsigned short* bS[2];                    \
  _Pragma("unroll")                                                            \
  for (int j = 0; j < 2; ++j) {                                                \
    aS[j] = A + (size_t)(m0 + (wave * 2 + j) * 16 + r4) * 2048 + scol;         \
    bS[j] = W + (size_t)(n0 + (wave * 2 + j) * 16 + r4) * 2048 + scol;         \
  }                                                                            \
  f32x4 acc[8][4] = {};

#define STAGE2(BUF, J)                                                         \
  do {                                                                         \
    gload16(aS[J], &lA[BUF][(wave * 2 + (J)) * 512]);                          \
    gload16(bS[J], &lB[BUF][(wave * 2 + (J)) * 512]);                          \
    aS[J] += 32; bS[J] += 32;                                                  \
  } while (0)

#define LDA4_(dst, MH, BUF)                                                    \
  do {                                                                         \
    _Pragma("unroll")                                                          \
    for (int im = 0; im < 4; ++im)                                             \
      dst[im] = *(const bf16x8*)&lA[BUF][(wr * 128 + (MH)*64 + im * 16 + lo) * 32 + \
                                         ((hi ^ ((lo >> 1) & 3)) << 3)];       \
  } while (0)

#define LDB4_(dst, BUF)                                                        \
  do {                                                                         \
    _Pragma("unroll")                                                          \
    for (int ni = 0; ni < 4; ++ni)                                             \
      dst[ni] = *(const bf16x8*)&lB[BUF][(wc * 64 + ni * 16 + lo) * 32 +       \
                                         ((hi ^ ((lo >> 1) & 3)) << 3)];       \
  } while (0)

#define MF16(MH, aF, bF)                                                       \
  do {                                                                         \
    __builtin_amdgcn_s_setprio(1);                                             \
    _Pragma("unroll")                                                          \
    for (int im = 0; im < 4; ++im)                                             \
      _Pragma("unroll")                                                        \
      for (int ni = 0; ni < 4; ++ni)                                           \
        acc[(MH)*4 + im][ni] = MFMA16(aF[im], bF[ni], acc[(MH)*4 + im][ni]);   \
    __builtin_amdgcn_s_setprio(0);                                             \
  } while (0)

#define BAR __builtin_amdgcn_s_barrier()
#define VMC(N) asm volatile("s_waitcnt vmcnt(" #N ")" ::: "memory")

// one K-tile, single barrier window; mh1 A-reads interleaved after mh0 MFMAs
#define TILE(RBUF, SBUF, COND, VN)                                             \
  do {                                                                         \
    bf16x8 aF[4], aG[4], bF[4];                                                \
    LDA4_(aF, 0, RBUF); LDB4_(bF, RBUF);                                       \
    if (COND) { STAGE2(SBUF, 0); STAGE2(SBUF, 1); }                            \
    BAR;                                                                       \
    MF16(0, aF, bF);                                                           \
    LDA4_(aG, 1, RBUF);                                                        \
    MF16(1, aG, bF);                                                           \
    VMC(VN); BAR;                                                              \
  } while (0)

#define GEMM_MAIN()                                                            \
  STAGE2(0, 0); STAGE2(0, 1); STAGE2(1, 0); STAGE2(1, 1);                      \
  STAGE2(2, 0); STAGE2(2, 1);                                                  \
  VMC(8); BAR;                                                                 \
  for (int u = 0; u < 15; ++u) {                                               \
    TILE(0, 3, true, 8); TILE(1, 0, true, 8);                                  \
    TILE(2, 1, true, 8); TILE(3, 2, true, 8);                                  \
  }                                                                            \
  TILE(0, 3, true, 8); TILE(1, 0, false, 4);                                   \
  TILE(2, 1, false, 0); TILE(3, 2, false, 0);

// ---------------------------------------------------------------------------
// QKV GEMM: M=8192 (B*S), N=6144 (Wq;Wk;Wv), K=2048. Output scattered into
// Q/K/V [b,nh,S,hd] bf16 with bias.
// ---------------------------------------------------------------------------
__global__ __launch_bounds__(512, 2)
void gemm_qkv(const unsigned short* __restrict__ A,
              const unsigned short* __restrict__ W,
              const float* __restrict__ bq, const float* __restrict__ bk,
              const float* __restrict__ bv,
              unsigned short* __restrict__ Q, unsigned short* __restrict__ Kq,
              unsigned short* __restrict__ V) {
  __shared__ unsigned short lA[4][256 * 32];
  __shared__ unsigned short lB[4][256 * 32];
  const int bid = blockIdx.x;
  const int sid = (bid & 7) * 96 + (bid >> 3);
  const int bm = sid / 24, bn = sid % 24;
  const int m0 = bm * 256, n0 = bn * 256;
  GEMM_PRE();
  GEMM_MAIN();

  const int which = n0 >> 11;
  const float* bias = (which == 0) ? bq : (which == 1) ? bk : bv;
  unsigned short* dst = (which == 0) ? Q : (which == 1) ? Kq : V;
#pragma unroll
  for (int mi = 0; mi < 8; mi++)
#pragma unroll
    for (int ni = 0; ni < 4; ni++) {
      int n_g = n0 + wc * 64 + ni * 16 + lo;
      int n2 = n_g & 2047;
      int head = n2 >> 7, d = n2 & 127;
      float bb = bias[n2];
#pragma unroll
      for (int i = 0; i < 4; i++) {
        int m = m0 + wr * 128 + mi * 16 + hi * 4 + i;
        int b = m >> 11, s = m & 2047;
        dst[(((size_t)b * 16 + head) * 2048 + s) * 128 + d] = f2bf(acc[mi][ni][i] + bb);
      }
    }
}

// ---------------------------------------------------------------------------
// Output GEMM: M=8192, N=2048, K=2048, fp32 out + bias.
// ---------------------------------------------------------------------------
__global__ __launch_bounds__(512, 2)
void gemm_out(const unsigned short* __restrict__ A,
              const unsigned short* __restrict__ W,
              const float* __restrict__ bo, float* __restrict__ out) {
  __shared__ unsigned short lA[4][256 * 32];
  __shared__ unsigned short lB[4][256 * 32];
  const int bid = blockIdx.x;
  const int sid = (bid & 7) * 32 + (bid >> 3);
  const int bm = sid >> 3, bn = sid & 7;
  const int m0 = bm * 256, n0 = bn * 256;
  GEMM_PRE();
  GEMM_MAIN();

#pragma unroll
  for (int mi = 0; mi < 8; mi++)
#pragma unroll
    for (int ni = 0; ni < 4; ni++) {
      int n_g = n0 + wc * 64 + ni * 16 + lo;
      float bb = bo[n_g];
#pragma unroll
      for (int i = 0; i < 4; i++) {
        int m = m0 + wr * 128 + mi * 16 + hi * 4 + i;
        out[(size_t)m * 2048 + n_g] = acc[mi][ni][i] + bb;
      }
    }
}

// ---------------------------------------------------------------------------
// Causal flash attention, KVBLK=64. Grid: 64 (bh) x 16 (q-tiles of 128).
// 4 waves/block, wave owns 32 q-rows (2 m-frags). Per 64-key tile:
// K staged swizzled (4 gload16/thread), V^T staged [d 0..127|ones][64 k]
// stride 72 (16B-aligned, odd-dword -> conflict-free b128), P [32][72].
// Softmax: log2 domain, defer-max (T13); l via ones-column MFMA (acc[*][8]).
// ---------------------------------------------------------------------------
__global__ __launch_bounds__(256, 2)
void attn_kernel(const unsigned short* __restrict__ Qb,
                 const unsigned short* __restrict__ Kb,
                 const unsigned short* __restrict__ Vb,
                 unsigned short* __restrict__ Ob) {
  __shared__ unsigned short lK[64 * 128];       // 16 KB, swizzled rows
  __shared__ unsigned short lVt[144 * 72];      // V^T + ones rows 128..143
  __shared__ unsigned short lP[4][32 * 72];     // per-wave P [32 q][64 k]

  const int tid = threadIdx.x;
  const int wave = tid >> 6, lane = tid & 63;
  const int lo = lane & 15, hi = lane >> 4;
  const int bh = blockIdx.x & 63;
  const int qt = 15 - (blockIdx.x >> 6);        // heavy tiles dispatched first
  const int q0 = qt * 128 + wave * 32;
  const size_t base = (size_t)bh * 2048 * 128;
  const float SCL = 0.08838834764831845f * 1.4426950408889634f;
  const float THR = 11.5416f;                   // 8 * log2(e)

  // ones rows (d=128..143, 64 cols); first use after 2 barriers
#pragma unroll
  for (int x = tid; x < 1024; x += 256)
    lVt[(128 + (x >> 6)) * 72 + (x & 63)] = 0x3F80;  // bf16 1.0

  // Q fragments: rows q0+mi*16+lo, d = dk*32 + hi*8 ..+7
  bf16x8 aq[2][4];
#pragma unroll
  for (int mi = 0; mi < 2; mi++)
#pragma unroll
    for (int dk = 0; dk < 4; dk++)
      aq[mi][dk] = *(const bf16x8*)&Qb[base + (size_t)(q0 + mi * 16 + lo) * 128 + dk * 32 + hi * 8];

  f32x4 acc[2][9] = {};                         // [.][8] = l (ones column)
  float mrun[2][4];
#pragma unroll
  for (int a = 0; a < 2; a++)
#pragma unroll
    for (int b = 0; b < 4; b++) mrun[a][b] = -INFINITY;

  const int ktn = qt * 2 + 2;                   // 64-key tiles to causal edge
  const int qmax_w = q0 + 31;

  for (int kt = 0; kt < ktn; kt++) {
    __syncthreads();
    // ---- stage K tile: rows j*16 + wave*4 + hi, swizzled source ----
#pragma unroll
    for (int j = 0; j < 4; j++) {
      int lrow = j * 16 + wave * 4 + hi;
      int srccol = (lo * 16) ^ ((lrow & 7) << 4);           // byte offset in 256B row
      gload16(Kb + base + (size_t)(kt * 64 + lrow) * 128 + (srccol >> 1),
              &lK[(j * 16 + wave * 4) * 128]);
    }
    // ---- stage V^T: thread -> k-rows {2rr,2rr+1}, d-cols cc..cc+7, 2 halves ----
    {
      int rr = tid & 31;
      int c0 = (tid >> 5) * 8;
#pragma unroll
      for (int half = 0; half < 2; half++) {
        int cc = c0 + half * 64;
        const unsigned short* vp = Vb + base + (size_t)(kt * 64 + 2 * rr) * 128 + cc;
        s16x8 va = *(const s16x8*)vp;
        s16x8 vb2 = *(const s16x8*)(vp + 128);
#pragma unroll
        for (int j = 0; j < 8; j++)
          *(ushort2*)&lVt[(cc + j) * 72 + 2 * rr] =
              make_ushort2((unsigned short)va[j], (unsigned short)vb2[j]);
      }
    }
    __syncthreads();

    if (kt * 64 <= qmax_w) {                    // wave-uniform: tile not fully masked
      // ---- scores: S[32q][64k] ----
      f32x4 sc[2][4] = {};
#pragma unroll
      for (int ni = 0; ni < 4; ni++)
#pragma unroll
        for (int dk = 0; dk < 4; dk++) {
          int row = ni * 16 + lo;
          int col = (dk * 32 + hi * 8) ^ ((row & 7) << 3);  // element-index swizzle
          bf16x8 bk_ = *(const bf16x8*)&lK[row * 128 + col];
          sc[0][ni] = MFMA16(aq[0][dk], bk_, sc[0][ni]);
          sc[1][ni] = MFMA16(aq[1][dk], bk_, sc[1][ni]);
        }

      // ---- scale + causal mask (log2 domain), defer-max condition ----
      float tm[2][4];
      bool cond = true;
#pragma unroll
      for (int mi = 0; mi < 2; mi++)
#pragma unroll
        for (int i = 0; i < 4; i++) {
          int qrow = q0 + mi * 16 + hi * 4 + i;
          float mx = -INFINITY;
#pragma unroll
          for (int ni = 0; ni < 4; ni++) {
            int kc = kt * 64 + ni * 16 + lo;
            float s = sc[mi][ni][i] * SCL;
            if (kc > qrow) s = -INFINITY;
            sc[mi][ni][i] = s;
            mx = fmaxf(mx, s);
          }
          tm[mi][i] = mx;
          cond = cond && (mx <= mrun[mi][i] + THR);
        }

      if (!__all((int)cond)) {
        // ---- slow path: per-row shfl max, rescale acc (incl. l column) ----
#pragma unroll
        for (int mi = 0; mi < 2; mi++)
#pragma unroll
          for (int i = 0; i < 4; i++) {
            float mt = tm[mi][i];
            mt = fmaxf(mt, __shfl_xor(mt, 1));
            mt = fmaxf(mt, __shfl_xor(mt, 2));
            mt = fmaxf(mt, __shfl_xor(mt, 4));
            mt = fmaxf(mt, __shfl_xor(mt, 8));
            float mo = mrun[mi][i];
            float mn = fmaxf(mo, mt);
            float alpha = exp2f(mo - mn);       // exp2(-inf)=0 handles first tile
            mrun[mi][i] = mn;
#pragma unroll
            for (int ni = 0; ni < 9; ni++) acc[mi][ni][i] *= alpha;
          }
      }

      // ---- P = exp2(s - m) -> per-wave LDS tile ----
      unsigned short* lPw = &lP[wave][0];
#pragma unroll
      for (int mi = 0; mi < 2; mi++)
#pragma unroll
        for (int i = 0; i < 4; i++) {
          float m = mrun[mi][i];
          int prow = mi * 16 + hi * 4 + i;
#pragma unroll
          for (int ni = 0; ni < 4; ni++)
            lPw[prow * 72 + ni * 16 + lo] = f2bf(exp2f(sc[mi][ni][i] - m));
        }

      // ---- PV: O += P[32x64] * V'[64x(128+16)] (ni=8 = ones -> l) ----
      bf16x8 ap[2][2];
#pragma unroll
      for (int mi = 0; mi < 2; mi++)
#pragma unroll
        for (int k2 = 0; k2 < 2; k2++)
          ap[mi][k2] = *(const bf16x8*)&lPw[(mi * 16 + lo) * 72 + k2 * 32 + hi * 8];
#pragma unroll
      for (int ni = 0; ni < 9; ni++)
#pragma unroll
        for (int k2 = 0; k2 < 2; k2++) {
          bf16x8 bv_ = *(const bf16x8*)&lVt[(ni * 16 + lo) * 72 + k2 * 32 + hi * 8];
          acc[0][ni] = MFMA16(ap[0][k2], bv_, acc[0][ni]);
          acc[1][ni] = MFMA16(ap[1][k2], bv_, acc[1][ni]);
        }
    }
  }

  // ---- epilogue: O[b, s, h*128+d] = acc / l, l = acc[mi][8][i] ----
  const int b = bh >> 4, hh = bh & 15;
#pragma unroll
  for (int mi = 0; mi < 2; mi++)
#pragma unroll
    for (int i = 0; i < 4; i++) {
      float inv = 1.0f / acc[mi][8][i];
      int s = q0 + mi * 16 + hi * 4 + i;
      size_t rowbase = ((size_t)b * 2048 + s) * 2048 + hh * 128 + lo;
#pragma unroll
      for (int ni = 0; ni < 8; ni++)
        Ob[rowbase + ni * 16] = f2bf(acc[mi][ni][i] * inv);
    }
}

// ---------------------------------------------------------------------------
extern "C" void kernel_launch(void* const* d_in, const int* in_sizes, int n_in,
                              void* d_out, int out_size, void* d_ws, size_t ws_size,
                              hipStream_t stream) {
  const float* h  = (const float*)d_in[0];
  const float* Wq = (const float*)d_in[1];
  const float* bq = (const float*)d_in[2];
  const float* Wk = (const float*)d_in[3];
  const float* bk = (const float*)d_in[4];
  const float* Wv = (const float*)d_in[5];
  const float* bv = (const float*)d_in[6];
  const float* Wo = (const float*)d_in[7];
  const float* bo = (const float*)d_in[8];
  float* out = (float*)d_out;

  char* ws = (char*)d_ws;
  unsigned short* h_bf  = (unsigned short*)(ws + 0);            // 32 MiB
  unsigned short* Qb    = (unsigned short*)(ws + 33554432);     // 32 MiB
  unsigned short* Kb    = (unsigned short*)(ws + 67108864);     // 32 MiB
  unsigned short* Vb    = (unsigned short*)(ws + 100663296);    // 32 MiB
  unsigned short* Wqkv  = (unsigned short*)(ws + 134217728);    // 24 MiB
  unsigned short* Wo_bf = (unsigned short*)(ws + 159383552);    // 8 MiB
  unsigned short* Ob    = h_bf;                                 // reuse after QKV GEMM

  // fp32 -> bf16 conversions
  cvt_kernel<<<16384, 256, 0, stream>>>(h, h_bf, 4194304);
  cvt_kernel<<<4096, 256, 0, stream>>>(Wq, Wqkv, 1048576);
  cvt_kernel<<<4096, 256, 0, stream>>>(Wk, Wqkv + 4194304, 1048576);
  cvt_kernel<<<4096, 256, 0, stream>>>(Wv, Wqkv + 8388608, 1048576);
  cvt_kernel<<<4096, 256, 0, stream>>>(Wo, Wo_bf, 1048576);

  // QKV projection (M=8192, N=6144, K=2048), 32x24 blocks of 256x256
  gemm_qkv<<<dim3(768), dim3(512), 0, stream>>>(h_bf, Wqkv, bq, bk, bv, Qb, Kb, Vb);

  // causal attention (64 bh x 16 q-tiles)
  attn_kernel<<<dim3(1024), dim3(256), 0, stream>>>(Qb, Kb, Vb, Ob);

  // output projection (M=8192, N=2048, K=2048), 32x8 blocks, fp32 out
  gemm_out<<<dim3(256), dim3(512), 0, stream>>>(Ob, Wo_bf, bo, out);
}

// Round 8
// 450.640 us; speedup vs baseline: 1.2389x; 1.0100x over previous
//
#include <hip/hip_runtime.h>
#include <hip/hip_bf16.h>
#include <math.h>

// ---------------------------------------------------------------------------
// GPT2 attention block: out = Attn(h) for B=4, S=2048, H=2048, nh=16, hd=128
// Pipeline (all bf16 MFMA, fp32 accumulate):
//   1) cvt fp32->bf16: h; fused [Wq;Wk;Wv;Wo]
//   2) gemm_qkv: 256^2-tile GEMM, BK=64, 2dbuf x 2khalf, vmcnt(4)/tile
//   3) attn: causal flash attn, KVBLK=64, K-dbuf prefetch, V issue-early
//   4) gemm_out: same GEMM core, O @ Wo^T + bo -> fp32 d_out
// ---------------------------------------------------------------------------

using bf16x8 = __attribute__((ext_vector_type(8))) __bf16;
using f32x4  = __attribute__((ext_vector_type(4))) float;
using s16x8  = __attribute__((ext_vector_type(8))) short;

#define MFMA16(a, b, c) __builtin_amdgcn_mfma_f32_16x16x32_bf16((a), (b), (c), 0, 0, 0)

__device__ __forceinline__ unsigned short f2bf(float f) {
  unsigned u = __float_as_uint(f);
  u += 0x7FFFu + ((u >> 16) & 1u);   // round-to-nearest-even (finite inputs only)
  return (unsigned short)(u >> 16);
}

__device__ __forceinline__ void gload16(const void* g, void* l) {
  __builtin_amdgcn_global_load_lds((const __attribute__((address_space(1))) void*)g,
                                   (__attribute__((address_space(3))) void*)l,
                                   16, 0, 0);
}

// ---------------------------------------------------------------------------
// fp32 -> bf16 converts
// ---------------------------------------------------------------------------
__global__ void cvt_kernel(const float* __restrict__ in, unsigned short* __restrict__ out, int n4) {
  int i = blockIdx.x * 256 + threadIdx.x;
  if (i >= n4) return;
  float4 v = ((const float4*)in)[i];
  ushort4 o;
  o.x = f2bf(v.x); o.y = f2bf(v.y); o.z = f2bf(v.z); o.w = f2bf(v.w);
  ((ushort4*)out)[i] = o;
}

// fused weight convert: Wq,Wk,Wv -> Wqkv (concat), Wo -> Wo_bf. 1M float4 each.
__global__ void cvtW_kernel(const float* __restrict__ s0, const float* __restrict__ s1,
                            const float* __restrict__ s2, const float* __restrict__ s3,
                            unsigned short* __restrict__ dqkv, unsigned short* __restrict__ dwo) {
  int i = blockIdx.x * 256 + threadIdx.x;
  int which = i >> 20;
  const float* s = (which == 0) ? s0 : (which == 1) ? s1 : (which == 2) ? s2 : s3;
  unsigned short* d = (which < 3) ? dqkv + which * 4194304 : dwo;
  int j = i & 1048575;
  float4 v = ((const float4*)s)[j];
  ushort4 o;
  o.x = f2bf(v.x); o.y = f2bf(v.y); o.z = f2bf(v.z); o.w = f2bf(v.w);
  ((ushort4*)d)[j] = o;
}

// ---------------------------------------------------------------------------
// 256x256-tile, BK=64, 8-wave (2Mx4N) GEMM core.
// LDS: lA/lB[2 dbuf][2 khalf][256*32] = 128 KiB. Tile t in buf t&1.
// 4 phases per tile: (kh0,mh0)(kh0,mh1)(kh1,mh0)(kh1,mh1), each phase
// {ds_read frags; stage 1 unit (2 gload_lds); BAR; 16 MFMA (setprio); BAR}.
// Stage rotation per tile t: ph1 A(t+1,kh1)->buf^1, ph2 B(t+1,kh1),
// ph3 A(t+2,kh0)->buf, ph4 B(t+2,kh0); single vmcnt(4) at tile end leaves
// exactly ph3-4's 2 units outstanding and guarantees tile t+1 fully staged.
// Region safety: each stage target's last ds_read was drained (lgkmcnt
// before MFMA) >=1 barrier-pair before the stage issues.
// Swizzle g(r)=(r>>1)&3 on 16B slots, both-sides (verified 0 conflicts).
// ---------------------------------------------------------------------------

#define GEMM_PRE()                                                             \
  const int tid = threadIdx.x;                                                 \
  const int wave = tid >> 6, lane = tid & 63;                                  \
  const int lo = lane & 15, hi = lane >> 4;                                    \
  const int wr = wave >> 2, wc = wave & 3;                                     \
  const int r4 = lane >> 2, s4 = lane & 3;                                     \
  const int scol = ((s4 ^ ((r4 >> 1) & 3)) << 3);                              \
  const unsigned short* aBase[2]; const unsigned short* bBase[2];              \
  _Pragma("unroll")                                                            \
  for (int j = 0; j < 2; ++j) {                                                \
    aBase[j] = A + (size_t)(m0 + (wave * 2 + j) * 16 + r4) * 2048 + scol;      \
    bBase[j] = W + (size_t)(n0 + (wave * 2 + j) * 16 + r4) * 2048 + scol;      \
  }                                                                            \
  f32x4 acc[8][4] = {};

#define STAGEA(BUF, KH, KOFF)                                                  \
  do {                                                                         \
    _Pragma("unroll")                                                          \
    for (int j = 0; j < 2; ++j)                                                \
      gload16(aBase[j] + (KOFF), &lA[BUF][KH][(wave * 2 + j) * 512]);          \
  } while (0)

#define STAGEB(BUF, KH, KOFF)                                                  \
  do {                                                                         \
    _Pragma("unroll")                                                          \
    for (int j = 0; j < 2; ++j)                                                \
      gload16(bBase[j] + (KOFF), &lB[BUF][KH][(wave * 2 + j) * 512]);          \
  } while (0)

#define LDA4_(dst, MH, BUF, KH)                                                \
  do {                                                                         \
    _Pragma("unroll")                                                          \
    for (int im = 0; im < 4; ++im)                                             \
      dst[im] = *(const bf16x8*)&lA[BUF][KH][(wr * 128 + (MH)*64 + im * 16 + lo) * 32 + \
                                             ((hi ^ ((lo >> 1) & 3)) << 3)];   \
  } while (0)

#define LDB4_(dst, BUF, KH)                                                    \
  do {                                                                         \
    _Pragma("unroll")                                                          \
    for (int ni = 0; ni < 4; ++ni)                                             \
      dst[ni] = *(const bf16x8*)&lB[BUF][KH][(wc * 64 + ni * 16 + lo) * 32 +   \
                                             ((hi ^ ((lo >> 1) & 3)) << 3)];   \
  } while (0)

#define MF16(MH, aF, bF)                                                       \
  do {                                                                         \
    __builtin_amdgcn_s_setprio(1);                                             \
    _Pragma("unroll")                                                          \
    for (int im = 0; im < 4; ++im)                                             \
      _Pragma("unroll")                                                        \
      for (int ni = 0; ni < 4; ++ni)                                           \
        acc[(MH)*4 + im][ni] = MFMA16(aF[im], bF[ni], acc[(MH)*4 + im][ni]);   \
    __builtin_amdgcn_s_setprio(0);                                             \
  } while (0)

#define BAR __builtin_amdgcn_s_barrier()
#define VMC(N) asm volatile("s_waitcnt vmcnt(" #N ")" ::: "memory")

// one BK=64 K-tile in buf B (BX = B^1). C1: stage (t+1) kh1; C2: stage (t+2) kh0.
#define TILE64(B, BX, C1, C2, VN)                                              \
  do {                                                                         \
    bf16x8 aF[4], aG[4], bF[4];                                                \
    LDA4_(aF, 0, B, 0); LDB4_(bF, B, 0);                                       \
    if (C1) STAGEA(BX, 1, kbase + 96);                                         \
    BAR; MF16(0, aF, bF); BAR;                                                 \
    LDA4_(aG, 1, B, 0);                                                        \
    if (C1) STAGEB(BX, 1, kbase + 96);                                         \
    BAR; MF16(1, aG, bF); BAR;                                                 \
    LDA4_(aF, 0, B, 1); LDB4_(bF, B, 1);                                       \
    if (C2) STAGEA(B, 0, kbase + 128);                                         \
    BAR; MF16(0, aF, bF); BAR;                                                 \
    LDA4_(aG, 1, B, 1);                                                        \
    if (C2) STAGEB(B, 0, kbase + 128);                                         \
    BAR; MF16(1, aG, bF); VMC(VN); BAR;                                        \
    kbase += 64;                                                               \
  } while (0)

#define GEMM_MAIN()                                                            \
  int kbase = 0;                                                               \
  STAGEA(0, 0, 0); STAGEB(0, 0, 0);                                            \
  STAGEA(0, 1, 32); STAGEB(0, 1, 32);                                          \
  STAGEA(1, 0, 64); STAGEB(1, 0, 64);                                          \
  VMC(4); BAR;                                                                 \
  for (int u = 0; u < 14; ++u) {                                               \
    TILE64(0, 1, true, true, 4); TILE64(1, 0, true, true, 4);                  \
  }                                                                            \
  TILE64(0, 1, true, true, 4);                                                 \
  TILE64(1, 0, true, true, 4);                                                 \
  TILE64(0, 1, true, false, 0);                                                \
  TILE64(1, 0, false, false, 0);

// ---------------------------------------------------------------------------
// QKV GEMM: M=8192 (B*S), N=6144 (Wq;Wk;Wv), K=2048. Output scattered into
// Q/K/V [b,nh,S,hd] bf16 with bias.
// ---------------------------------------------------------------------------
__global__ __launch_bounds__(512, 2)
void gemm_qkv(const unsigned short* __restrict__ A,
              const unsigned short* __restrict__ W,
              const float* __restrict__ bq, const float* __restrict__ bk,
              const float* __restrict__ bv,
              unsigned short* __restrict__ Q, unsigned short* __restrict__ Kq,
              unsigned short* __restrict__ V) {
  __shared__ unsigned short lA[2][2][256 * 32];
  __shared__ unsigned short lB[2][2][256 * 32];
  const int bid = blockIdx.x;
  const int sid = (bid & 7) * 96 + (bid >> 3);
  const int bm = sid / 24, bn = sid % 24;
  const int m0 = bm * 256, n0 = bn * 256;
  GEMM_PRE();
  GEMM_MAIN();

  const int which = n0 >> 11;
  const float* bias = (which == 0) ? bq : (which == 1) ? bk : bv;
  unsigned short* dst = (which == 0) ? Q : (which == 1) ? Kq : V;
#pragma unroll
  for (int mi = 0; mi < 8; mi++)
#pragma unroll
    for (int ni = 0; ni < 4; ni++) {
      int n_g = n0 + wc * 64 + ni * 16 + lo;
      int n2 = n_g & 2047;
      int head = n2 >> 7, d = n2 & 127;
      float bb = bias[n2];
#pragma unroll
      for (int i = 0; i < 4; i++) {
        int m = m0 + wr * 128 + mi * 16 + hi * 4 + i;
        int b = m >> 11, s = m & 2047;
        dst[(((size_t)b * 16 + head) * 2048 + s) * 128 + d] = f2bf(acc[mi][ni][i] + bb);
      }
    }
}

// ---------------------------------------------------------------------------
// Output GEMM: M=8192, N=2048, K=2048, fp32 out + bias.
// ---------------------------------------------------------------------------
__global__ __launch_bounds__(512, 2)
void gemm_out(const unsigned short* __restrict__ A,
              const unsigned short* __restrict__ W,
              const float* __restrict__ bo, float* __restrict__ out) {
  __shared__ unsigned short lA[2][2][256 * 32];
  __shared__ unsigned short lB[2][2][256 * 32];
  const int bid = blockIdx.x;
  const int sid = (bid & 7) * 32 + (bid >> 3);
  const int bm = sid >> 3, bn = sid & 7;
  const int m0 = bm * 256, n0 = bn * 256;
  GEMM_PRE();
  GEMM_MAIN();

#pragma unroll
  for (int mi = 0; mi < 8; mi++)
#pragma unroll
    for (int ni = 0; ni < 4; ni++) {
      int n_g = n0 + wc * 64 + ni * 16 + lo;
      float bb = bo[n_g];
#pragma unroll
      for (int i = 0; i < 4; i++) {
        int m = m0 + wr * 128 + mi * 16 + hi * 4 + i;
        out[(size_t)m * 2048 + n_g] = acc[mi][ni][i] + bb;
      }
    }
}

// ---------------------------------------------------------------------------
// Causal flash attention, KVBLK=64, K double-buffered with counted-vmcnt
// prefetch; V issue-early/write-late (T14). Grid: 64 bh x 16 q-tiles.
// Per kt: {V gloads -> regs; K(kt+1) gload_lds -> lK[(kt+1)&1]; vmcnt(8)
// drains K(kt); BAR; QK^T + softmax + P-writes; vmcnt(4) readies V regs;
// V^T ds_write; lgkmcnt(0); BAR; PV}. Raw barriers only (no vmcnt(0) drain).
// Softmax: log2 domain, defer-max (T13); l via ones-column MFMA (acc[*][8]).
// ---------------------------------------------------------------------------
__global__ __launch_bounds__(256, 2)
void attn_kernel(const unsigned short* __restrict__ Qb,
                 const unsigned short* __restrict__ Kb,
                 const unsigned short* __restrict__ Vb,
                 unsigned short* __restrict__ Ob) {
  __shared__ unsigned short lK[2][64 * 128];    // 2 x 16 KB, swizzled rows
  __shared__ unsigned short lVt[144 * 72];      // V^T + ones rows 128..143
  __shared__ unsigned short lP[4][32 * 72];     // per-wave P [32 q][64 k]

  const int tid = threadIdx.x;
  const int wave = tid >> 6, lane = tid & 63;
  const int lo = lane & 15, hi = lane >> 4;
  const int bh = blockIdx.x & 63;
  const int qt = 15 - (blockIdx.x >> 6);        // heavy tiles dispatched first
  const int q0 = qt * 128 + wave * 32;
  const size_t base = (size_t)bh * 2048 * 128;
  const float SCL = 0.08838834764831845f * 1.4426950408889634f;
  const float THR = 11.5416f;                   // 8 * log2(e)

  // ones rows (d=128..143, 64 cols); visible to all by first PV's barrier
#pragma unroll
  for (int x = tid; x < 1024; x += 256)
    lVt[(128 + (x >> 6)) * 72 + (x & 63)] = 0x3F80;  // bf16 1.0

  // Q fragments: rows q0+mi*16+lo, d = dk*32 + hi*8 ..+7
  bf16x8 aq[2][4];
#pragma unroll
  for (int mi = 0; mi < 2; mi++)
#pragma unroll
    for (int dk = 0; dk < 4; dk++)
      aq[mi][dk] = *(const bf16x8*)&Qb[base + (size_t)(q0 + mi * 16 + lo) * 128 + dk * 32 + hi * 8];

  f32x4 acc[2][9] = {};                         // [.][8] = l (ones column)
  float mrun[2][4];
#pragma unroll
  for (int a = 0; a < 2; a++)
#pragma unroll
    for (int b = 0; b < 4; b++) mrun[a][b] = -INFINITY;

  const int ktn = qt * 2 + 2;                   // 64-key tiles to causal edge
  const int qmax_w = q0 + 31;
  const int rr = tid & 31, c0v = (tid >> 5) * 8;

#define STAGEK(KT2, BUF)                                                       \
  do {                                                                         \
    _Pragma("unroll")                                                          \
    for (int j = 0; j < 4; j++) {                                              \
      int lrow = j * 16 + wave * 4 + hi;                                       \
      int srccol = (lo * 16) ^ ((lrow & 7) << 4);                              \
      gload16(Kb + base + (size_t)((KT2) * 64 + lrow) * 128 + (srccol >> 1),   \
              &lK[BUF][(j * 16 + wave * 4) * 128]);                            \
    }                                                                          \
  } while (0)

  STAGEK(0, 0);

  for (int kt = 0; kt < ktn; kt++) {
    // ---- V issue-early (4 global loads to regs) ----
    const unsigned short* vp0 = Vb + base + (size_t)(kt * 64 + 2 * rr) * 128 + c0v;
    s16x8 v00 = *(const s16x8*)vp0;
    s16x8 v01 = *(const s16x8*)(vp0 + 128);
    s16x8 v10 = *(const s16x8*)(vp0 + 64);
    s16x8 v11 = *(const s16x8*)(vp0 + 192);
    // ---- K(kt+1) prefetch; drain K(kt) only ----
    if (kt + 1 < ktn) { STAGEK(kt + 1, (kt + 1) & 1); VMC(8); }
    else { VMC(4); }
    BAR;                                        // K(kt) visible to all waves

    const bool docomp = (kt * 64 <= qmax_w);
    if (docomp) {
      // ---- scores: S[32q][64k] from lK[kt&1] ----
      const unsigned short* lKc = &lK[kt & 1][0];
      f32x4 sc[2][4] = {};
#pragma unroll
      for (int ni = 0; ni < 4; ni++)
#pragma unroll
        for (int dk = 0; dk < 4; dk++) {
          int row = ni * 16 + lo;
          int col = (dk * 32 + hi * 8) ^ ((row & 7) << 3);
          bf16x8 bk_ = *(const bf16x8*)&lKc[row * 128 + col];
          sc[0][ni] = MFMA16(aq[0][dk], bk_, sc[0][ni]);
          sc[1][ni] = MFMA16(aq[1][dk], bk_, sc[1][ni]);
        }
      // ---- scale + causal mask, defer-max ----
      float tm[2][4];
      bool cond = true;
#pragma unroll
      for (int mi = 0; mi < 2; mi++)
#pragma unroll
        for (int i = 0; i < 4; i++) {
          int qrow = q0 + mi * 16 + hi * 4 + i;
          float mx = -INFINITY;
#pragma unroll
          for (int ni = 0; ni < 4; ni++) {
            int kc = kt * 64 + ni * 16 + lo;
            float s = sc[mi][ni][i] * SCL;
            if (kc > qrow) s = -INFINITY;
            sc[mi][ni][i] = s;
            mx = fmaxf(mx, s);
          }
          tm[mi][i] = mx;
          cond = cond && (mx <= mrun[mi][i] + THR);
        }
      if (!__all((int)cond)) {
#pragma unroll
        for (int mi = 0; mi < 2; mi++)
#pragma unroll
          for (int i = 0; i < 4; i++) {
            float mt = tm[mi][i];
            mt = fmaxf(mt, __shfl_xor(mt, 1));
            mt = fmaxf(mt, __shfl_xor(mt, 2));
            mt = fmaxf(mt, __shfl_xor(mt, 4));
            mt = fmaxf(mt, __shfl_xor(mt, 8));
            float mo = mrun[mi][i];
            float mn = fmaxf(mo, mt);
            float alpha = exp2f(mo - mn);
            mrun[mi][i] = mn;
#pragma unroll
            for (int ni = 0; ni < 9; ni++) acc[mi][ni][i] *= alpha;
          }
      }
      // ---- P = exp2(s - m) -> per-wave LDS tile (private, no sync) ----
      unsigned short* lPw = &lP[wave][0];
#pragma unroll
      for (int mi = 0; mi < 2; mi++)
#pragma unroll
        for (int i = 0; i < 4; i++) {
          float m = mrun[mi][i];
          int prow = mi * 16 + hi * 4 + i;
#pragma unroll
          for (int ni = 0; ni < 4; ni++)
            lPw[prow * 72 + ni * 16 + lo] = f2bf(exp2f(sc[mi][ni][i] - m));
        }
    }

    // ---- V write-late: regs ready after counted wait (K(kt+1) stays out) ----
    if (kt + 1 < ktn) VMC(4); else VMC(0);
#pragma unroll
    for (int j = 0; j < 8; j++) {
      *(ushort2*)&lVt[(c0v + j) * 72 + 2 * rr] =
          make_ushort2((unsigned short)v00[j], (unsigned short)v01[j]);
      *(ushort2*)&lVt[(c0v + 64 + j) * 72 + 2 * rr] =
          make_ushort2((unsigned short)v10[j], (unsigned short)v11[j]);
    }
    asm volatile("s_waitcnt lgkmcnt(0)" ::: "memory");
    BAR;                                        // lVt(kt) visible

    if (docomp) {
      // ---- PV: O += P[32x64] * V'[64x(128+16)] (ni=8 = ones -> l) ----
      unsigned short* lPw = &lP[wave][0];
      bf16x8 ap[2][2];
#pragma unroll
      for (int mi = 0; mi < 2; mi++)
#pragma unroll
        for (int k2 = 0; k2 < 2; k2++)
          ap[mi][k2] = *(const bf16x8*)&lPw[(mi * 16 + lo) * 72 + k2 * 32 + hi * 8];
#pragma unroll
      for (int ni = 0; ni < 9; ni++)
#pragma unroll
        for (int k2 = 0; k2 < 2; k2++) {
          bf16x8 bv_ = *(const bf16x8*)&lVt[(ni * 16 + lo) * 72 + k2 * 32 + hi * 8];
          acc[0][ni] = MFMA16(ap[0][k2], bv_, acc[0][ni]);
          acc[1][ni] = MFMA16(ap[1][k2], bv_, acc[1][ni]);
        }
    }
  }

  // ---- epilogue: O[b, s, h*128+d] = acc / l, l = acc[mi][8][i] ----
  const int b = bh >> 4, hh = bh & 15;
#pragma unroll
  for (int mi = 0; mi < 2; mi++)
#pragma unroll
    for (int i = 0; i < 4; i++) {
      float inv = 1.0f / acc[mi][8][i];
      int s = q0 + mi * 16 + hi * 4 + i;
      size_t rowbase = ((size_t)b * 2048 + s) * 2048 + hh * 128 + lo;
#pragma unroll
      for (int ni = 0; ni < 8; ni++)
        Ob[rowbase + ni * 16] = f2bf(acc[mi][ni][i] * inv);
    }
}

// ---------------------------------------------------------------------------
extern "C" void kernel_launch(void* const* d_in, const int* in_sizes, int n_in,
                              void* d_out, int out_size, void* d_ws, size_t ws_size,
                              hipStream_t stream) {
  const float* h  = (const float*)d_in[0];
  const float* Wq = (const float*)d_in[1];
  const float* bq = (const float*)d_in[2];
  const float* Wk = (const float*)d_in[3];
  const float* bk = (const float*)d_in[4];
  const float* Wv = (const float*)d_in[5];
  const float* bv = (const float*)d_in[6];
  const float* Wo = (const float*)d_in[7];
  const float* bo = (const float*)d_in[8];
  float* out = (float*)d_out;

  char* ws = (char*)d_ws;
  unsigned short* h_bf  = (unsigned short*)(ws + 0);            // 32 MiB
  unsigned short* Qb    = (unsigned short*)(ws + 33554432);     // 32 MiB
  unsigned short* Kb    = (unsigned short*)(ws + 67108864);     // 32 MiB
  unsigned short* Vb    = (unsigned short*)(ws + 100663296);    // 32 MiB
  unsigned short* Wqkv  = (unsigned short*)(ws + 134217728);    // 24 MiB
  unsigned short* Wo_bf = (unsigned short*)(ws + 159383552);    // 8 MiB
  unsigned short* Ob    = h_bf;                                 // reuse after QKV GEMM

  // fp32 -> bf16 conversions (h; fused weights)
  cvt_kernel<<<16384, 256, 0, stream>>>(h, h_bf, 4194304);
  cvtW_kernel<<<16384, 256, 0, stream>>>(Wq, Wk, Wv, Wo, Wqkv, Wo_bf);

  // QKV projection (M=8192, N=6144, K=2048), 32x24 blocks of 256x256
  gemm_qkv<<<dim3(768), dim3(512), 0, stream>>>(h_bf, Wqkv, bq, bk, bv, Qb, Kb, Vb);

  // causal attention (64 bh x 16 q-tiles)
  attn_kernel<<<dim3(1024), dim3(256), 0, stream>>>(Qb, Kb, Vb, Ob);

  // output projection (M=8192, N=2048, K=2048), 32x8 blocks, fp32 out
  gemm_out<<<dim3(256), dim3(512), 0, stream>>>(Ob, Wo_bf, bo, out);
}

// Round 9
// 431.802 us; speedup vs baseline: 1.2929x; 1.0436x over previous
//
#include <hip/hip_runtime.h>
#include <hip/hip_bf16.h>
#include <math.h>

// ---------------------------------------------------------------------------
// GPT2 attention block: out = Attn(h) for B=4, S=2048, H=2048, nh=16, hd=128
// Pipeline (all bf16 MFMA, fp32 accumulate):
//   1) cvt fp32->bf16: h; fused [Wq;Wk;Wv;Wo]
//   2) gemm_qkv: 256^2-tile GEMM (BK=32, 4-buf, stage-ahead-3, vmcnt(8))
//   3) attn: causal flash attn, KVBLK=64, K-dbuf prefetch, V issue-early
//   4) gemm_out: same GEMM core, O @ Wo^T + bo -> fp32 d_out
// ---------------------------------------------------------------------------

using bf16x8 = __attribute__((ext_vector_type(8))) __bf16;
using f32x4  = __attribute__((ext_vector_type(4))) float;
using s16x8  = __attribute__((ext_vector_type(8))) short;

#define MFMA16(a, b, c) __builtin_amdgcn_mfma_f32_16x16x32_bf16((a), (b), (c), 0, 0, 0)

__device__ __forceinline__ unsigned short f2bf(float f) {
  unsigned u = __float_as_uint(f);
  u += 0x7FFFu + ((u >> 16) & 1u);   // round-to-nearest-even (finite inputs only)
  return (unsigned short)(u >> 16);
}

__device__ __forceinline__ void gload16(const void* g, void* l) {
  __builtin_amdgcn_global_load_lds((const __attribute__((address_space(1))) void*)g,
                                   (__attribute__((address_space(3))) void*)l,
                                   16, 0, 0);
}

// ---------------------------------------------------------------------------
// fp32 -> bf16 converts
// ---------------------------------------------------------------------------
__global__ void cvt_kernel(const float* __restrict__ in, unsigned short* __restrict__ out, int n4) {
  int i = blockIdx.x * 256 + threadIdx.x;
  if (i >= n4) return;
  float4 v = ((const float4*)in)[i];
  ushort4 o;
  o.x = f2bf(v.x); o.y = f2bf(v.y); o.z = f2bf(v.z); o.w = f2bf(v.w);
  ((ushort4*)out)[i] = o;
}

// fused weight convert: Wq,Wk,Wv -> Wqkv (concat), Wo -> Wo_bf. 1M float4 each.
__global__ void cvtW_kernel(const float* __restrict__ s0, const float* __restrict__ s1,
                            const float* __restrict__ s2, const float* __restrict__ s3,
                            unsigned short* __restrict__ dqkv, unsigned short* __restrict__ dwo) {
  int i = blockIdx.x * 256 + threadIdx.x;
  int which = i >> 20;
  const float* s = (which == 0) ? s0 : (which == 1) ? s1 : (which == 2) ? s2 : s3;
  unsigned short* d = (which < 3) ? dqkv + which * 4194304 : dwo;
  int j = i & 1048575;
  float4 v = ((const float4*)s)[j];
  ushort4 o;
  o.x = f2bf(v.x); o.y = f2bf(v.y); o.z = f2bf(v.z); o.w = f2bf(v.w);
  ((ushort4*)d)[j] = o;
}

// ---------------------------------------------------------------------------
// 256x256-tile, BK=32, 8-wave (2Mx4N) GEMM core, counted-vmcnt pipeline.
// (round-6 core, measured best: 215 us / MfmaUtil 42% / 0 bank conflicts)
// LDS: 4 buffers x (A[256][32] + B[256][32]) bf16 = 128 KiB. Tile t reads
// buf t%4, stages tile t+3 into (t+3)%4 (= buf of t-1, fully consumed before
// t-1's closing barrier). Steady wait vmcnt(8) at tile end; tail 8/4/0/0.
// Swizzle g(r)=(r>>1)&3 on 16B slots, both-sides (verified 0 conflicts).
// ---------------------------------------------------------------------------

#define GEMM_PRE()                                                             \
  const int tid = threadIdx.x;                                                 \
  const int wave = tid >> 6, lane = tid & 63;                                  \
  const int lo = lane & 15, hi = lane >> 4;                                    \
  const int wr = wave >> 2, wc = wave & 3;                                     \
  const int r4 = lane >> 2, s4 = lane & 3;                                     \
  const int scol = ((s4 ^ ((r4 >> 1) & 3)) << 3);                              \
  const unsigned short* aS[2]; const unsigned short* bS[2];                    \
  _Pragma("unroll")                                                            \
  for (int j = 0; j < 2; ++j) {                                                \
    aS[j] = A + (size_t)(m0 + (wave * 2 + j) * 16 + r4) * 2048 + scol;         \
    bS[j] = W + (size_t)(n0 + (wave * 2 + j) * 16 + r4) * 2048 + scol;         \
  }                                                                            \
  f32x4 acc[8][4] = {};

#define STAGE2(BUF, J)                                                         \
  do {                                                                         \
    gload16(aS[J], &lA[BUF][(wave * 2 + (J)) * 512]);                          \
    gload16(bS[J], &lB[BUF][(wave * 2 + (J)) * 512]);                          \
    aS[J] += 32; bS[J] += 32;                                                  \
  } while (0)

#define LDA4_(dst, MH, BUF)                                                    \
  do {                                                                         \
    _Pragma("unroll")                                                          \
    for (int im = 0; im < 4; ++im)                                             \
      dst[im] = *(const bf16x8*)&lA[BUF][(wr * 128 + (MH)*64 + im * 16 + lo) * 32 + \
                                         ((hi ^ ((lo >> 1) & 3)) << 3)];       \
  } while (0)

#define LDB4_(dst, BUF)                                                        \
  do {                                                                         \
    _Pragma("unroll")                                                          \
    for (int ni = 0; ni < 4; ++ni)                                             \
      dst[ni] = *(const bf16x8*)&lB[BUF][(wc * 64 + ni * 16 + lo) * 32 +       \
                                         ((hi ^ ((lo >> 1) & 3)) << 3)];       \
  } while (0)

#define MF16(MH, aF, bF)                                                       \
  do {                                                                         \
    __builtin_amdgcn_s_setprio(1);                                             \
    _Pragma("unroll")                                                          \
    for (int im = 0; im < 4; ++im)                                             \
      _Pragma("unroll")                                                        \
      for (int ni = 0; ni < 4; ++ni)                                           \
        acc[(MH)*4 + im][ni] = MFMA16(aF[im], bF[ni], acc[(MH)*4 + im][ni]);   \
    __builtin_amdgcn_s_setprio(0);                                             \
  } while (0)

#define BAR __builtin_amdgcn_s_barrier()
#define VMC(N) asm volatile("s_waitcnt vmcnt(" #N ")" ::: "memory")

#define TILE(RBUF, SBUF, COND, VN)                                             \
  do {                                                                         \
    bf16x8 aF[4], aG[4], bF[4];                                                \
    LDA4_(aF, 0, RBUF); LDB4_(bF, RBUF);                                       \
    if (COND) STAGE2(SBUF, 0);                                                 \
    BAR; MF16(0, aF, bF); BAR;                                                 \
    LDA4_(aG, 1, RBUF);                                                        \
    if (COND) STAGE2(SBUF, 1);                                                 \
    BAR; MF16(1, aG, bF); VMC(VN); BAR;                                        \
  } while (0)

#define GEMM_MAIN()                                                            \
  STAGE2(0, 0); STAGE2(0, 1); STAGE2(1, 0); STAGE2(1, 1);                      \
  STAGE2(2, 0); STAGE2(2, 1);                                                  \
  VMC(8); BAR;                                                                 \
  for (int u = 0; u < 15; ++u) {                                               \
    TILE(0, 3, true, 8); TILE(1, 0, true, 8);                                  \
    TILE(2, 1, true, 8); TILE(3, 2, true, 8);                                  \
  }                                                                            \
  TILE(0, 3, true, 8); TILE(1, 0, false, 4);                                   \
  TILE(2, 1, false, 0); TILE(3, 2, false, 0);

// ---------------------------------------------------------------------------
// QKV GEMM: M=8192 (B*S), N=6144 (Wq;Wk;Wv), K=2048. Output scattered into
// Q/K/V [b,nh,S,hd] bf16 with bias.
// ---------------------------------------------------------------------------
__global__ __launch_bounds__(512, 2)
void gemm_qkv(const unsigned short* __restrict__ A,
              const unsigned short* __restrict__ W,
              const float* __restrict__ bq, const float* __restrict__ bk,
              const float* __restrict__ bv,
              unsigned short* __restrict__ Q, unsigned short* __restrict__ Kq,
              unsigned short* __restrict__ V) {
  __shared__ unsigned short lA[4][256 * 32];
  __shared__ unsigned short lB[4][256 * 32];
  const int bid = blockIdx.x;
  const int sid = (bid & 7) * 96 + (bid >> 3);
  const int bm = sid / 24, bn = sid % 24;
  const int m0 = bm * 256, n0 = bn * 256;
  GEMM_PRE();
  GEMM_MAIN();

  const int which = n0 >> 11;
  const float* bias = (which == 0) ? bq : (which == 1) ? bk : bv;
  unsigned short* dst = (which == 0) ? Q : (which == 1) ? Kq : V;
#pragma unroll
  for (int mi = 0; mi < 8; mi++)
#pragma unroll
    for (int ni = 0; ni < 4; ni++) {
      int n_g = n0 + wc * 64 + ni * 16 + lo;
      int n2 = n_g & 2047;
      int head = n2 >> 7, d = n2 & 127;
      float bb = bias[n2];
#pragma unroll
      for (int i = 0; i < 4; i++) {
        int m = m0 + wr * 128 + mi * 16 + hi * 4 + i;
        int b = m >> 11, s = m & 2047;
        dst[(((size_t)b * 16 + head) * 2048 + s) * 128 + d] = f2bf(acc[mi][ni][i] + bb);
      }
    }
}

// ---------------------------------------------------------------------------
// Output GEMM: M=8192, N=2048, K=2048, fp32 out + bias.
// ---------------------------------------------------------------------------
__global__ __launch_bounds__(512, 2)
void gemm_out(const unsigned short* __restrict__ A,
              const unsigned short* __restrict__ W,
              const float* __restrict__ bo, float* __restrict__ out) {
  __shared__ unsigned short lA[4][256 * 32];
  __shared__ unsigned short lB[4][256 * 32];
  const int bid = blockIdx.x;
  const int sid = (bid & 7) * 32 + (bid >> 3);
  const int bm = sid >> 3, bn = sid & 7;
  const int m0 = bm * 256, n0 = bn * 256;
  GEMM_PRE();
  GEMM_MAIN();

#pragma unroll
  for (int mi = 0; mi < 8; mi++)
#pragma unroll
    for (int ni = 0; ni < 4; ni++) {
      int n_g = n0 + wc * 64 + ni * 16 + lo;
      float bb = bo[n_g];
#pragma unroll
      for (int i = 0; i < 4; i++) {
        int m = m0 + wr * 128 + mi * 16 + hi * 4 + i;
        out[(size_t)m * 2048 + n_g] = acc[mi][ni][i] + bb;
      }
    }
}

// ---------------------------------------------------------------------------
// Causal flash attention, KVBLK=64, K double-buffered with counted-vmcnt
// prefetch; V issue-early/write-late (T14). Grid: 64 bh x 16 q-tiles.
// Per kt: {V gloads -> regs; K(kt+1) gload_lds -> lK[(kt+1)&1]; vmcnt(8)
// drains K(kt) AND V regs (V loads are the 4 oldest); BAR; QK^T + softmax
// + P-writes; V^T ds_write (compiler waits cover V regs; K prefetch stays
// in flight); lgkmcnt(0); BAR; PV}. setprio around MFMA clusters (T5; attn
// blocks are not barrier-locked across the 2 blocks/CU).
// Softmax: log2 domain, defer-max (T13); l via ones-column MFMA (acc[*][8]).
// ---------------------------------------------------------------------------
__global__ __launch_bounds__(256, 2)
void attn_kernel(const unsigned short* __restrict__ Qb,
                 const unsigned short* __restrict__ Kb,
                 const unsigned short* __restrict__ Vb,
                 unsigned short* __restrict__ Ob) {
  __shared__ unsigned short lK[2][64 * 128];    // 2 x 16 KB, swizzled rows
  __shared__ unsigned short lVt[144 * 72];      // V^T + ones rows 128..143
  __shared__ unsigned short lP[4][32 * 72];     // per-wave P [32 q][64 k]

  const int tid = threadIdx.x;
  const int wave = tid >> 6, lane = tid & 63;
  const int lo = lane & 15, hi = lane >> 4;
  const int bh = blockIdx.x & 63;
  const int qt = 15 - (blockIdx.x >> 6);        // heavy tiles dispatched first
  const int q0 = qt * 128 + wave * 32;
  const size_t base = (size_t)bh * 2048 * 128;
  const float SCL = 0.08838834764831845f * 1.4426950408889634f;
  const float THR = 11.5416f;                   // 8 * log2(e)

  // ones rows (d=128..143, 64 cols); visible to all by first PV's barrier
#pragma unroll
  for (int x = tid; x < 1024; x += 256)
    lVt[(128 + (x >> 6)) * 72 + (x & 63)] = 0x3F80;  // bf16 1.0

  // Q fragments: rows q0+mi*16+lo, d = dk*32 + hi*8 ..+7
  bf16x8 aq[2][4];
#pragma unroll
  for (int mi = 0; mi < 2; mi++)
#pragma unroll
    for (int dk = 0; dk < 4; dk++)
      aq[mi][dk] = *(const bf16x8*)&Qb[base + (size_t)(q0 + mi * 16 + lo) * 128 + dk * 32 + hi * 8];

  f32x4 acc[2][9] = {};                         // [.][8] = l (ones column)
  float mrun[2][4];
#pragma unroll
  for (int a = 0; a < 2; a++)
#pragma unroll
    for (int b = 0; b < 4; b++) mrun[a][b] = -INFINITY;

  const int ktn = qt * 2 + 2;                   // 64-key tiles to causal edge
  const int qmax_w = q0 + 31;
  const int rr = tid & 31, c0v = (tid >> 5) * 8;

#define STAGEK(KT2, BUF)                                                       \
  do {                                                                         \
    _Pragma("unroll")                                                          \
    for (int j = 0; j < 4; j++) {                                              \
      int lrow = j * 16 + wave * 4 + hi;                                       \
      int srccol = (lo * 16) ^ ((lrow & 7) << 4);                              \
      gload16(Kb + base + (size_t)((KT2) * 64 + lrow) * 128 + (srccol >> 1),   \
              &lK[BUF][(j * 16 + wave * 4) * 128]);                            \
    }                                                                          \
  } while (0)

  STAGEK(0, 0);

  for (int kt = 0; kt < ktn; kt++) {
    // ---- V issue-early (4 global loads to regs; oldest in vmcnt queue) ----
    const unsigned short* vp0 = Vb + base + (size_t)(kt * 64 + 2 * rr) * 128 + c0v;
    s16x8 v00 = *(const s16x8*)vp0;
    s16x8 v01 = *(const s16x8*)(vp0 + 128);
    s16x8 v10 = *(const s16x8*)(vp0 + 64);
    s16x8 v11 = *(const s16x8*)(vp0 + 192);
    // ---- K(kt+1) prefetch; drain K(kt)+V only (K(kt+1) stays in flight) ----
    if (kt + 1 < ktn) { STAGEK(kt + 1, (kt + 1) & 1); VMC(8); }
    else { VMC(0); }
    BAR;                                        // K(kt) visible to all waves

    const bool docomp = (kt * 64 <= qmax_w);
    if (docomp) {
      // ---- scores: S[32q][64k] from lK[kt&1] ----
      const unsigned short* lKc = &lK[kt & 1][0];
      f32x4 sc[2][4] = {};
      __builtin_amdgcn_s_setprio(1);
#pragma unroll
      for (int ni = 0; ni < 4; ni++)
#pragma unroll
        for (int dk = 0; dk < 4; dk++) {
          int row = ni * 16 + lo;
          int col = (dk * 32 + hi * 8) ^ ((row & 7) << 3);
          bf16x8 bk_ = *(const bf16x8*)&lKc[row * 128 + col];
          sc[0][ni] = MFMA16(aq[0][dk], bk_, sc[0][ni]);
          sc[1][ni] = MFMA16(aq[1][dk], bk_, sc[1][ni]);
        }
      __builtin_amdgcn_s_setprio(0);
      // ---- scale + causal mask, defer-max ----
      float tm[2][4];
      bool cond = true;
#pragma unroll
      for (int mi = 0; mi < 2; mi++)
#pragma unroll
        for (int i = 0; i < 4; i++) {
          int qrow = q0 + mi * 16 + hi * 4 + i;
          float mx = -INFINITY;
#pragma unroll
          for (int ni = 0; ni < 4; ni++) {
            int kc = kt * 64 + ni * 16 + lo;
            float s = sc[mi][ni][i] * SCL;
            if (kc > qrow) s = -INFINITY;
            sc[mi][ni][i] = s;
            mx = fmaxf(mx, s);
          }
          tm[mi][i] = mx;
          cond = cond && (mx <= mrun[mi][i] + THR);
        }
      if (!__all((int)cond)) {
#pragma unroll
        for (int mi = 0; mi < 2; mi++)
#pragma unroll
          for (int i = 0; i < 4; i++) {
            float mt = tm[mi][i];
            mt = fmaxf(mt, __shfl_xor(mt, 1));
            mt = fmaxf(mt, __shfl_xor(mt, 2));
            mt = fmaxf(mt, __shfl_xor(mt, 4));
            mt = fmaxf(mt, __shfl_xor(mt, 8));
            float mo = mrun[mi][i];
            float mn = fmaxf(mo, mt);
            float alpha = exp2f(mo - mn);
            mrun[mi][i] = mn;
#pragma unroll
            for (int ni = 0; ni < 9; ni++) acc[mi][ni][i] *= alpha;
          }
      }
      // ---- P = exp2(s - m) -> per-wave LDS tile (private, no sync) ----
      unsigned short* lPw = &lP[wave][0];
#pragma unroll
      for (int mi = 0; mi < 2; mi++)
#pragma unroll
        for (int i = 0; i < 4; i++) {
          float m = mrun[mi][i];
          int prow = mi * 16 + hi * 4 + i;
#pragma unroll
          for (int ni = 0; ni < 4; ni++)
            lPw[prow * 72 + ni * 16 + lo] = f2bf(exp2f(sc[mi][ni][i] - m));
        }
    }

    // ---- V write-late (compiler-inserted waits cover the V regs) ----
#pragma unroll
    for (int j = 0; j < 8; j++) {
      *(ushort2*)&lVt[(c0v + j) * 72 + 2 * rr] =
          make_ushort2((unsigned short)v00[j], (unsigned short)v01[j]);
      *(ushort2*)&lVt[(c0v + 64 + j) * 72 + 2 * rr] =
          make_ushort2((unsigned short)v10[j], (unsigned short)v11[j]);
    }
    asm volatile("s_waitcnt lgkmcnt(0)" ::: "memory");
    BAR;                                        // lVt(kt) visible

    if (docomp) {
      // ---- PV: O += P[32x64] * V'[64x(128+16)] (ni=8 = ones -> l) ----
      unsigned short* lPw = &lP[wave][0];
      bf16x8 ap[2][2];
#pragma unroll
      for (int mi = 0; mi < 2; mi++)
#pragma unroll
        for (int k2 = 0; k2 < 2; k2++)
          ap[mi][k2] = *(const bf16x8*)&lPw[(mi * 16 + lo) * 72 + k2 * 32 + hi * 8];
      __builtin_amdgcn_s_setprio(1);
#pragma unroll
      for (int ni = 0; ni < 9; ni++)
#pragma unroll
        for (int k2 = 0; k2 < 2; k2++) {
          bf16x8 bv_ = *(const bf16x8*)&lVt[(ni * 16 + lo) * 72 + k2 * 32 + hi * 8];
          acc[0][ni] = MFMA16(ap[0][k2], bv_, acc[0][ni]);
          acc[1][ni] = MFMA16(ap[1][k2], bv_, acc[1][ni]);
        }
      __builtin_amdgcn_s_setprio(0);
    }
  }

  // ---- epilogue: O[b, s, h*128+d] = acc / l, l = acc[mi][8][i] ----
  const int b = bh >> 4, hh = bh & 15;
#pragma unroll
  for (int mi = 0; mi < 2; mi++)
#pragma unroll
    for (int i = 0; i < 4; i++) {
      float inv = 1.0f / acc[mi][8][i];
      int s = q0 + mi * 16 + hi * 4 + i;
      size_t rowbase = ((size_t)b * 2048 + s) * 2048 + hh * 128 + lo;
#pragma unroll
      for (int ni = 0; ni < 8; ni++)
        Ob[rowbase + ni * 16] = f2bf(acc[mi][ni][i] * inv);
    }
}

// ---------------------------------------------------------------------------
extern "C" void kernel_launch(void* const* d_in, const int* in_sizes, int n_in,
                              void* d_out, int out_size, void* d_ws, size_t ws_size,
                              hipStream_t stream) {
  const float* h  = (const float*)d_in[0];
  const float* Wq = (const float*)d_in[1];
  const float* bq = (const float*)d_in[2];
  const float* Wk = (const float*)d_in[3];
  const float* bk = (const float*)d_in[4];
  const float* Wv = (const float*)d_in[5];
  const float* bv = (const float*)d_in[6];
  const float* Wo = (const float*)d_in[7];
  const float* bo = (const float*)d_in[8];
  float* out = (float*)d_out;

  char* ws = (char*)d_ws;
  unsigned short* h_bf  = (unsigned short*)(ws + 0);            // 32 MiB
  unsigned short* Qb    = (unsigned short*)(ws + 33554432);     // 32 MiB
  unsigned short* Kb    = (unsigned short*)(ws + 67108864);     // 32 MiB
  unsigned short* Vb    = (unsigned short*)(ws + 100663296);    // 32 MiB
  unsigned short* Wqkv  = (unsigned short*)(ws + 134217728);    // 24 MiB
  unsigned short* Wo_bf = (unsigned short*)(ws + 159383552);    // 8 MiB
  unsigned short* Ob    = h_bf;                                 // reuse after QKV GEMM

  // fp32 -> bf16 conversions (h; fused weights)
  cvt_kernel<<<16384, 256, 0, stream>>>(h, h_bf, 4194304);
  cvtW_kernel<<<16384, 256, 0, stream>>>(Wq, Wk, Wv, Wo, Wqkv, Wo_bf);

  // QKV projection (M=8192, N=6144, K=2048), 32x24 blocks of 256x256
  gemm_qkv<<<dim3(768), dim3(512), 0, stream>>>(h_bf, Wqkv, bq, bk, bv, Qb, Kb, Vb);

  // causal attention (64 bh x 16 q-tiles)
  attn_kernel<<<dim3(1024), dim3(256), 0, stream>>>(Qb, Kb, Vb, Ob);

  // output projection (M=8192, N=2048, K=2048), 32x8 blocks, fp32 out
  gemm_out<<<dim3(256), dim3(512), 0, stream>>>(Ob, Wo_bf, bo, out);
}